// Round 14
// baseline (1084.257 us; speedup 1.0000x reference)
//
#include <hip/hip_runtime.h>

#define HH 128
#define WW 128
#define HWP (HH*WW)
#define NC 64
#define NB 2
#define NN 5
#define OFFC 144
#define NKC 18                    // K-chunks of 32 per 576-K conv pass

typedef __attribute__((ext_vector_type(8))) _Float16 half8;
typedef __attribute__((ext_vector_type(4))) float floatx4;
typedef __attribute__((ext_vector_type(2))) float floatx2;

// out[b, center=2] = x_center
__global__ __launch_bounds__(256) void copy_center_k(const float* __restrict__ xc,
                                                     float* __restrict__ out) {
    int idx = blockIdx.x * 256 + threadIdx.x;
    const int total = NB * 3 * HWP;
    if (idx >= total) return;
    int b = idx / (3 * HWP);
    int r = idx - b * 3 * HWP;
    out[(size_t)((b * NN + 2) * 3) * HWP + r] = xc[idx];
}

// Repack planar pf frame -> channel-last [px][64]. is_ref: blockIdx.y = b (center frame);
// else blockIdx.y = jl (supp frame of job job0+jl). LDS 64x65 transpose tile.
__global__ __launch_bounds__(256) void repack_k(const float* __restrict__ pf,
                                                float* __restrict__ dst, int job0, int is_ref)
{
    __shared__ float T[64][65];
    const int jl = blockIdx.y;
    const float* src;
    if (is_ref) {
        src = pf + (size_t)((jl * NN + 2) * NC) * HWP;
    } else {
        int jg = job0 + jl;
        int b = jg & 1, fi = jg >> 1;
        int frame = fi + (fi >= 2 ? 1 : 0);
        src = pf + (size_t)((b * NN + frame) * NC) * HWP;
    }
    float* d = dst + (size_t)jl * NC * HWP;
    const int p0 = blockIdx.x * 64;
    const int tid = threadIdx.x;
    const int lx = tid & 63, cg4 = tid >> 6;
#pragma unroll
    for (int cc = 0; cc < 16; ++cc) {
        int c = cc * 4 + cg4;
        T[c][lx] = src[(size_t)c * HWP + p0 + lx];
    }
    __syncthreads();
    const int px = tid >> 2, c0 = (tid & 3) * 16;
#pragma unroll
    for (int j = 0; j < 4; ++j) {
        floatx4 v = { T[c0 + j*4 + 0][px], T[c0 + j*4 + 1][px],
                      T[c0 + j*4 + 2][px], T[c0 + j*4 + 3][px] };
        *(floatx4*)(d + (size_t)(p0 + px) * 64 + c0 + j*4) = v;
    }
}

// Weight preprocessor, SPLIT-fp16: w[co][cin_src][9] -> wp[ct][kc][{hi,lo}][lane][8],
// k = kc*32 + (lane>>4)*8 + j.
// mode 0 (conv, nkc=18):   kk = k>>6, ci = k&63 (+ci_off).
// mode 1 (deform, nkc=20): r = k/160, kr = k%160; kr<144: g = r*2 + kr/72,
//                          kk = (kr%72)>>3, cg = kr&7, ci = g*8+cg; else zero pad.
__global__ __launch_bounds__(256) void prew_k(const float* __restrict__ w,
                                              _Float16* __restrict__ wp,
                                              int nct, int nkc, int mode,
                                              int ci_off, int cin_src)
{
    int idx = blockIdx.x * 256 + threadIdx.x;
    if (idx >= nct * nkc * 64) return;
    int lane = idx & 63;
    int kc = (idx >> 6) % nkc;
    int ct = (idx >> 6) / nkc;
    int m = lane & 15, quad = lane >> 4;
    int co = ct * 16 + m;
    union { half8 v; _Float16 e[8]; } ph, pl;
#pragma unroll
    for (int j = 0; j < 8; ++j) {
        int k = kc * 32 + quad * 8 + j;
        float f = 0.f;
        if (mode == 0) {
            int kk = k >> 6, ci = k & 63;
            f = w[((size_t)co * cin_src + ci_off + ci) * 9 + kk];
        } else {
            int r = k / 160, kr = k - r * 160;
            if (kr < 144) {
                int g = r * 2 + kr / 72;
                int rr = kr % 72;
                int kk = rr >> 3, cg = rr & 7;
                f = w[((size_t)co * cin_src + g * 8 + cg) * 9 + kk];
            }
        }
        _Float16 h = (_Float16)f;
        ph.e[j] = h; pl.e[j] = (_Float16)(f - (float)h);
    }
    size_t base = (size_t)((ct * nkc + kc) * 2) * 512;
    *(half8*)(wp + base + lane * 8) = ph.v;
    *(half8*)(wp + base + 512 + lane * 8) = pl.v;
}

// SPLIT-fp16 MFMA 3x3 conv, CHANNEL-LAST src & dst. R16 structure + R18
// A-BATCH HOIST + R22 DEPTH-1 A-PIPELINE (proven). Two named A-register
// sets (E/O), kc unrolled 2x; every A-batch issues a full MFMA-block before
// first use. Only <9,0,0> instantiated (cr pair now fused in mcrconv_k).
template<int NCT, int SRCMODE, int ADD>
__global__ __launch_bounds__(256, 2) void mconv_k(
    const float* __restrict__ src, const float* __restrict__ R,
    const float* __restrict__ S, const _Float16* __restrict__ wp,
    const float* __restrict__ bias, float* __restrict__ out, int job0)
{
    constexpr int PL = 1456;              // 10*18*8 = 1440 + 16 pad (fp16 elems)
    constexpr int Ct = NCT * 16;
    const int jl = blockIdx.y, jg = job0 + jl;
    const int b = jg & 1;
    const int tile = blockIdx.x;          // 8 in x, 16 in y
    const int ty0 = (tile >> 3) << 3, tx0 = (tile & 7) << 4;
    const int tid = threadIdx.x;
    const int lane = tid & 63;
    const int wq = __builtin_amdgcn_readfirstlane(tid >> 6);
    const int n = lane & 15, quad = lane >> 4;

    const float* s0;
    if (SRCMODE == 0)      s0 = src + (size_t)jl * NC * HWP;
    else if (SRCMODE == 1) s0 = R + (size_t)b * NC * HWP;
    else                   s0 = S + (size_t)jl * NC * HWP;

    __shared__ _Float16 hh[8 * PL];
    __shared__ _Float16 ll[8 * PL];

    for (int t = tid; t < 360; t += 256) {
        int px = t >> 1, hf = t & 1;
        int hy = px / 18, hx = px - hy * 18;
        int gy = ty0 - 1 + hy, gx = tx0 - 1 + hx;
        bool ok = (gy >= 0 && gy < HH && gx >= 0 && gx < WW);
        const float* sp = s0 + (ok ? ((size_t)(gy * WW + gx) * 64) : 0) + hf * 32;
        int lb = px * 8;
#pragma unroll
        for (int c = 0; c < 4; ++c) {
            int cb = hf * 4 + c;
            floatx4 f0 = {0.f,0.f,0.f,0.f}, f1 = {0.f,0.f,0.f,0.f};
            if (ok) {
                f0 = *(const floatx4*)(sp + c * 8);
                f1 = *(const floatx4*)(sp + c * 8 + 4);
            }
            union { half8 v; _Float16 e[8]; } ph, pl;
#pragma unroll
            for (int j = 0; j < 4; ++j) {
                _Float16 h0 = (_Float16)f0[j], h1 = (_Float16)f1[j];
                ph.e[j] = h0;     ph.e[j+4] = h1;
                pl.e[j] = (_Float16)(f0[j] - (float)h0);
                pl.e[j+4] = (_Float16)(f1[j] - (float)h1);
            }
            *(half8*)&hh[cb * PL + lb] = ph.v;
            *(half8*)&ll[cb * PL + lb] = pl.v;
        }
    }
    __syncthreads();

    floatx4 acc0[NCT], acc1[NCT];
#pragma unroll
    for (int ct = 0; ct < NCT; ++ct) {
        acc0[ct] = floatx4{0.f, 0.f, 0.f, 0.f};
        acc1[ct] = floatx4{0.f, 0.f, 0.f, 0.f};
    }
    const int y0 = wq * 2, y1 = y0 + 1;

    half8 AhE[NCT], AlE[NCT], AhO[NCT], AlO[NCT];
    // prologue: A-batch for kc=0 into E
    {
        const _Float16* wk0 = wp + lane * 8;
#pragma unroll
        for (int ct = 0; ct < NCT; ++ct) {
            const _Float16* wc = wk0 + (size_t)ct * NKC * 1024;
            AhE[ct] = *(const half8*)wc;
            AlE[ct] = *(const half8*)(wc + 512);
        }
    }
#pragma unroll
    for (int kc2 = 0; kc2 < NKC; kc2 += 2) {
        // ---- even kc = kc2: prefetch O = A(kc2+1), MFMA from E ----
        {
            const int kc = kc2;
            const _Float16* wkn = wp + (size_t)(kc + 1) * 1024 + lane * 8;
#pragma unroll
            for (int ct = 0; ct < NCT; ++ct) {
                const _Float16* wc = wkn + (size_t)ct * NKC * 1024;
                AhO[ct] = *(const half8*)wc;
                AlO[ct] = *(const half8*)(wc + 512);
            }
            const int kk = kc >> 1;
            const int dy = kk / 3, dx = kk % 3;
            const int cb = ((kc & 1) << 2) + quad;
            const int ix0 = cb * PL + ((y0 + dy) * 18 + n + dx) * 8;
            const int ix1 = cb * PL + ((y1 + dy) * 18 + n + dx) * 8;
            half8 B0h = *(const half8*)&hh[ix0];
            half8 B0l = *(const half8*)&ll[ix0];
            half8 B1h = *(const half8*)&hh[ix1];
            half8 B1l = *(const half8*)&ll[ix1];
#pragma unroll
            for (int ct = 0; ct < NCT; ++ct) {
                acc0[ct] = __builtin_amdgcn_mfma_f32_16x16x32_f16(AhE[ct], B0h, acc0[ct], 0, 0, 0);
                acc0[ct] = __builtin_amdgcn_mfma_f32_16x16x32_f16(AhE[ct], B0l, acc0[ct], 0, 0, 0);
                acc0[ct] = __builtin_amdgcn_mfma_f32_16x16x32_f16(AlE[ct], B0h, acc0[ct], 0, 0, 0);
                acc1[ct] = __builtin_amdgcn_mfma_f32_16x16x32_f16(AhE[ct], B1h, acc1[ct], 0, 0, 0);
                acc1[ct] = __builtin_amdgcn_mfma_f32_16x16x32_f16(AhE[ct], B1l, acc1[ct], 0, 0, 0);
                acc1[ct] = __builtin_amdgcn_mfma_f32_16x16x32_f16(AlE[ct], B1h, acc1[ct], 0, 0, 0);
            }
        }
        // ---- odd kc = kc2+1: prefetch E = A(kc2+2) (if any), MFMA from O ----
        {
            const int kc = kc2 + 1;
            if (kc2 + 2 < NKC) {
                const _Float16* wkn = wp + (size_t)(kc2 + 2) * 1024 + lane * 8;
#pragma unroll
                for (int ct = 0; ct < NCT; ++ct) {
                    const _Float16* wc = wkn + (size_t)ct * NKC * 1024;
                    AhE[ct] = *(const half8*)wc;
                    AlE[ct] = *(const half8*)(wc + 512);
                }
            }
            const int kk = kc >> 1;
            const int dy = kk / 3, dx = kk % 3;
            const int cb = ((kc & 1) << 2) + quad;
            const int ix0 = cb * PL + ((y0 + dy) * 18 + n + dx) * 8;
            const int ix1 = cb * PL + ((y1 + dy) * 18 + n + dx) * 8;
            half8 B0h = *(const half8*)&hh[ix0];
            half8 B0l = *(const half8*)&ll[ix0];
            half8 B1h = *(const half8*)&hh[ix1];
            half8 B1l = *(const half8*)&ll[ix1];
#pragma unroll
            for (int ct = 0; ct < NCT; ++ct) {
                acc0[ct] = __builtin_amdgcn_mfma_f32_16x16x32_f16(AhO[ct], B0h, acc0[ct], 0, 0, 0);
                acc0[ct] = __builtin_amdgcn_mfma_f32_16x16x32_f16(AhO[ct], B0l, acc0[ct], 0, 0, 0);
                acc0[ct] = __builtin_amdgcn_mfma_f32_16x16x32_f16(AlO[ct], B0h, acc0[ct], 0, 0, 0);
                acc1[ct] = __builtin_amdgcn_mfma_f32_16x16x32_f16(AhO[ct], B1h, acc1[ct], 0, 0, 0);
                acc1[ct] = __builtin_amdgcn_mfma_f32_16x16x32_f16(AhO[ct], B1l, acc1[ct], 0, 0, 0);
                acc1[ct] = __builtin_amdgcn_mfma_f32_16x16x32_f16(AlO[ct], B1h, acc1[ct], 0, 0, 0);
            }
        }
    }

    const int oy0 = ty0 + y0, oy1 = ty0 + y1, ox = tx0 + n;
#pragma unroll
    for (int ct = 0; ct < NCT; ++ct) {
        const floatx4 b4 = *(const floatx4*)(bias + ct * 16 + quad * 4);
        float* op0 = out + ((size_t)jl * HWP + (size_t)oy0 * WW + ox) * Ct
                         + ct * 16 + quad * 4;
        float* op1 = out + ((size_t)jl * HWP + (size_t)oy1 * WW + ox) * Ct
                         + ct * 16 + quad * 4;
        floatx4 v0 = acc0[ct], v1 = acc1[ct];
        if (ADD) {
            v0 += *(const floatx4*)op0;
            v1 += *(const floatx4*)op1;
        } else {
            v0 += b4;
            v1 += b4;
        }
        *(floatx4*)op0 = v0;
        *(floatx4*)op1 = v1;
    }
}

// R25: FUSED cr-conv — fea1 = conv(concat(ref,supp)) in ONE kernel.
// Previously two dispatches: pass1 writes A = half0(R)+bias, pass2 does a
// full RMW of A with half1(S). The K-halves are independent accumulations
// into the same registers: stage R-tile -> K-loop(wp0) -> barrier ->
// restage S-tile -> K-loop(wp1) -> single C-write. Eliminates one dispatch
// (launch + drain), the 4 MB/job intermediate read, and one C-write pass.
// Body per half = proven R22 E/O pipeline (NCT=4). LDS unchanged 46.6 KB.
__global__ __launch_bounds__(256, 2) void mcrconv_k(
    const float* __restrict__ R, const float* __restrict__ S,
    const _Float16* __restrict__ wp0, const _Float16* __restrict__ wp1,
    const float* __restrict__ bias, float* __restrict__ out, int job0)
{
    constexpr int NCT = 4;
    constexpr int PL = 1456;
    constexpr int Ct = 64;
    const int jl = blockIdx.y, jg = job0 + jl;
    const int b = jg & 1;
    const int tile = blockIdx.x;          // 8 in x, 16 in y
    const int ty0 = (tile >> 3) << 3, tx0 = (tile & 7) << 4;
    const int tid = threadIdx.x;
    const int lane = tid & 63;
    const int wq = __builtin_amdgcn_readfirstlane(tid >> 6);
    const int n = lane & 15, quad = lane >> 4;

    __shared__ _Float16 hh[8 * PL];
    __shared__ _Float16 ll[8 * PL];

    floatx4 acc0[NCT], acc1[NCT];
#pragma unroll
    for (int ct = 0; ct < NCT; ++ct) {
        acc0[ct] = floatx4{0.f, 0.f, 0.f, 0.f};
        acc1[ct] = floatx4{0.f, 0.f, 0.f, 0.f};
    }
    const int y0 = wq * 2, y1 = y0 + 1;

#pragma unroll
    for (int h = 0; h < 2; ++h) {
        const float* s0 = (h == 0) ? (R + (size_t)b * NC * HWP)
                                   : (S + (size_t)jl * NC * HWP);
        const _Float16* wp = (h == 0) ? wp0 : wp1;
        if (h) __syncthreads();           // all waves done reading h=0 tiles
        for (int t = tid; t < 360; t += 256) {
            int px = t >> 1, hf = t & 1;
            int hy = px / 18, hx = px - hy * 18;
            int gy = ty0 - 1 + hy, gx = tx0 - 1 + hx;
            bool ok = (gy >= 0 && gy < HH && gx >= 0 && gx < WW);
            const float* sp = s0 + (ok ? ((size_t)(gy * WW + gx) * 64) : 0) + hf * 32;
            int lb = px * 8;
#pragma unroll
            for (int c = 0; c < 4; ++c) {
                int cb = hf * 4 + c;
                floatx4 f0 = {0.f,0.f,0.f,0.f}, f1 = {0.f,0.f,0.f,0.f};
                if (ok) {
                    f0 = *(const floatx4*)(sp + c * 8);
                    f1 = *(const floatx4*)(sp + c * 8 + 4);
                }
                union { half8 v; _Float16 e[8]; } ph, pl;
#pragma unroll
                for (int j = 0; j < 4; ++j) {
                    _Float16 h0 = (_Float16)f0[j], h1 = (_Float16)f1[j];
                    ph.e[j] = h0;     ph.e[j+4] = h1;
                    pl.e[j] = (_Float16)(f0[j] - (float)h0);
                    pl.e[j+4] = (_Float16)(f1[j] - (float)h1);
                }
                *(half8*)&hh[cb * PL + lb] = ph.v;
                *(half8*)&ll[cb * PL + lb] = pl.v;
            }
        }
        __syncthreads();

        half8 AhE[NCT], AlE[NCT], AhO[NCT], AlO[NCT];
        {
            const _Float16* wk0 = wp + lane * 8;
#pragma unroll
            for (int ct = 0; ct < NCT; ++ct) {
                const _Float16* wc = wk0 + (size_t)ct * NKC * 1024;
                AhE[ct] = *(const half8*)wc;
                AlE[ct] = *(const half8*)(wc + 512);
            }
        }
#pragma unroll
        for (int kc2 = 0; kc2 < NKC; kc2 += 2) {
            {
                const int kc = kc2;
                const _Float16* wkn = wp + (size_t)(kc + 1) * 1024 + lane * 8;
#pragma unroll
                for (int ct = 0; ct < NCT; ++ct) {
                    const _Float16* wc = wkn + (size_t)ct * NKC * 1024;
                    AhO[ct] = *(const half8*)wc;
                    AlO[ct] = *(const half8*)(wc + 512);
                }
                const int kk = kc >> 1;
                const int dy = kk / 3, dx = kk % 3;
                const int cb = ((kc & 1) << 2) + quad;
                const int ix0 = cb * PL + ((y0 + dy) * 18 + n + dx) * 8;
                const int ix1 = cb * PL + ((y1 + dy) * 18 + n + dx) * 8;
                half8 B0h = *(const half8*)&hh[ix0];
                half8 B0l = *(const half8*)&ll[ix0];
                half8 B1h = *(const half8*)&hh[ix1];
                half8 B1l = *(const half8*)&ll[ix1];
#pragma unroll
                for (int ct = 0; ct < NCT; ++ct) {
                    acc0[ct] = __builtin_amdgcn_mfma_f32_16x16x32_f16(AhE[ct], B0h, acc0[ct], 0, 0, 0);
                    acc0[ct] = __builtin_amdgcn_mfma_f32_16x16x32_f16(AhE[ct], B0l, acc0[ct], 0, 0, 0);
                    acc0[ct] = __builtin_amdgcn_mfma_f32_16x16x32_f16(AlE[ct], B0h, acc0[ct], 0, 0, 0);
                    acc1[ct] = __builtin_amdgcn_mfma_f32_16x16x32_f16(AhE[ct], B1h, acc1[ct], 0, 0, 0);
                    acc1[ct] = __builtin_amdgcn_mfma_f32_16x16x32_f16(AhE[ct], B1l, acc1[ct], 0, 0, 0);
                    acc1[ct] = __builtin_amdgcn_mfma_f32_16x16x32_f16(AlE[ct], B1h, acc1[ct], 0, 0, 0);
                }
            }
            {
                const int kc = kc2 + 1;
                if (kc2 + 2 < NKC) {
                    const _Float16* wkn = wp + (size_t)(kc2 + 2) * 1024 + lane * 8;
#pragma unroll
                    for (int ct = 0; ct < NCT; ++ct) {
                        const _Float16* wc = wkn + (size_t)ct * NKC * 1024;
                        AhE[ct] = *(const half8*)wc;
                        AlE[ct] = *(const half8*)(wc + 512);
                    }
                }
                const int kk = kc >> 1;
                const int dy = kk / 3, dx = kk % 3;
                const int cb = ((kc & 1) << 2) + quad;
                const int ix0 = cb * PL + ((y0 + dy) * 18 + n + dx) * 8;
                const int ix1 = cb * PL + ((y1 + dy) * 18 + n + dx) * 8;
                half8 B0h = *(const half8*)&hh[ix0];
                half8 B0l = *(const half8*)&ll[ix0];
                half8 B1h = *(const half8*)&hh[ix1];
                half8 B1l = *(const half8*)&ll[ix1];
#pragma unroll
                for (int ct = 0; ct < NCT; ++ct) {
                    acc0[ct] = __builtin_amdgcn_mfma_f32_16x16x32_f16(AhO[ct], B0h, acc0[ct], 0, 0, 0);
                    acc0[ct] = __builtin_amdgcn_mfma_f32_16x16x32_f16(AhO[ct], B0l, acc0[ct], 0, 0, 0);
                    acc0[ct] = __builtin_amdgcn_mfma_f32_16x16x32_f16(AlO[ct], B0h, acc0[ct], 0, 0, 0);
                    acc1[ct] = __builtin_amdgcn_mfma_f32_16x16x32_f16(AhO[ct], B1h, acc1[ct], 0, 0, 0);
                    acc1[ct] = __builtin_amdgcn_mfma_f32_16x16x32_f16(AhO[ct], B1l, acc1[ct], 0, 0, 0);
                    acc1[ct] = __builtin_amdgcn_mfma_f32_16x16x32_f16(AlO[ct], B1h, acc1[ct], 0, 0, 0);
                }
            }
        }
    }

    const int oy0 = ty0 + y0, oy1 = ty0 + y1, ox = tx0 + n;
#pragma unroll
    for (int ct = 0; ct < NCT; ++ct) {
        const floatx4 b4 = *(const floatx4*)(bias + ct * 16 + quad * 4);
        float* op0 = out + ((size_t)jl * HWP + (size_t)oy0 * WW + ox) * Ct
                         + ct * 16 + quad * 4;
        float* op1 = out + ((size_t)jl * HWP + (size_t)oy1 * WW + ox) * Ct
                         + ct * 16 + quad * 4;
        *(floatx4*)op0 = acc0[ct] + b4;
        *(floatx4*)op1 = acc1[ct] + b4;
    }
}

// Deformable conv, MFMA phase B (split-fp16). CHANNEL-LAST.
// R16: LDS-STAGED GATHER (proven). R19: de-paired phase A (proven).
// R21: offset prefetch + unrolled phase A (proven). R23 reverted.
__global__ __launch_bounds__(512, 4) void mdeform_k(
    const float* __restrict__ in, const float* __restrict__ off,
    const _Float16* __restrict__ wp, const float* __restrict__ bias,
    float* __restrict__ out, int supp_mode, const float* __restrict__ S)
{
    constexpr int SROW = 166;
    const int jl = blockIdx.y;
    const int tile = blockIdx.x;          // 16x16 tiles of 8x8
    const int ty0 = (tile >> 4) << 3, tx0 = (tile & 15) << 3;
    const int tid = threadIdx.x;
    const int lane = tid & 63;
    const int w8 = __builtin_amdgcn_readfirstlane(tid >> 6);  // wave 0..7
    const int q4 = w8 >> 1;               // co-tile 0..3
    const int sb2 = (w8 & 1) << 1;        // px-slot base: 0 or 2
    const int n = lane & 15, quad = lane >> 4;

    const float* ibase = supp_mode ? (S + (size_t)jl * NC * HWP)
                                   : (in + (size_t)jl * NC * HWP);
    const float* obase = off + (size_t)jl * OFFC * HWP;

    __shared__ _Float16 sh[64 * SROW];
    __shared__ _Float16 sl[64 * SROW];
    __shared__ float stg[256 * 16];       // 16x16 region x 16ch, quad-swizzled

    // zero pad K-slots [144,160)
    for (int e = tid; e < 64 * 16; e += 512) {
        int row = e >> 4, col = 144 + (e & 15);
        sh[row * SROW + col] = (_Float16)0.f;
        sl[row * SROW + col] = (_Float16)0.f;
    }

    floatx4 acc[2];
#pragma unroll
    for (int s = 0; s < 2; ++s) acc[s] = floatx4{0.f, 0.f, 0.f, 0.f};

    for (int r = 0; r < 4; ++r) {
        // ---- R21: prefetch this r's offsets (independent global loads; their
        // latency drains under the staging wait + barrier below)
        floatx2 o2v[3];
#pragma unroll
        for (int i = 0; i < 3; ++i) {
            int idx = tid + (i << 9);
            if (idx < 1152) {
                int gl = idx / 576;
                int rem = idx - gl * 576;
                int kk = rem >> 6;
                int px = rem & 63;
                int g = r * 2 + gl;
                int yy = ty0 + (px >> 3), xx = tx0 + (px & 7);
                o2v[i] = *(const floatx2*)(obase + (size_t)(yy * WW + xx) * OFFC
                                           + (g * 9 + kk) * 2);
            }
        }
        // ---- stage input region for this r's 16 channels (overlaps prev phase B)
#pragma unroll
        for (int j = 0; j < 2; ++j) {
            int t = tid + (j << 9);           // 0..1023
            int slot = t >> 2;                // 0..255 = ry*16+rx
            int qq = t & 3;
            int ry = slot >> 4, rx = slot & 15;
            int gy = ty0 - 4 + ry, gx = tx0 - 4 + rx;
            if ((unsigned)gy < (unsigned)HH && (unsigned)gx < (unsigned)WW) {
                floatx4 v = *(const floatx4*)(ibase + (size_t)(gy * WW + gx) * 64
                                              + r * 16 + qq * 4);
                *(floatx4*)&stg[(slot << 4) + ((qq ^ ((slot >> 1) & 3)) << 2)] = v;
            }
        }
        __syncthreads();   // staging visible; prev phase B done reading sh/sl
        // ---- phase A: de-paired tasks, UNROLLED. 1152 = 2(gl) x 9(kk) x 64(px)
#pragma unroll
        for (int i = 0; i < 3; ++i) {
            int idx = tid + (i << 9);         // 0..1535, active < 1152
            if (idx < 1152) {
                int gl = idx / 576;
                int rem = idx - gl * 576;
                int kk = rem >> 6;
                int px = rem & 63;
                int g = r * 2 + gl;
                int yy = ty0 + (px >> 3), xx = tx0 + (px & 7);
                floatx2 o2 = o2v[i];
                float pyf = (float)(yy + (kk / 3) - 1) + o2[0];
                float pxf = (float)(xx + (kk % 3) - 1) + o2[1];
                float fy = floorf(pyf), fx = floorf(pxf);
                float wy = pyf - fy, wx = pxf - fx;
                int y0 = (int)fy, x0 = (int)fx;
                int y1 = y0 + 1, x1 = x0 + 1;
                float m00 = (y0 >= 0 && y0 < HH && x0 >= 0 && x0 < WW) ? 1.f : 0.f;
                float m01 = (y0 >= 0 && y0 < HH && x1 >= 0 && x1 < WW) ? 1.f : 0.f;
                float m10 = (y1 >= 0 && y1 < HH && x0 >= 0 && x0 < WW) ? 1.f : 0.f;
                float m11 = (y1 >= 0 && y1 < HH && x1 >= 0 && x1 < WW) ? 1.f : 0.f;
                float w00 = (1.f - wy) * (1.f - wx) * m00;
                float w01 = (1.f - wy) * wx * m01;
                float w10 = wy * (1.f - wx) * m10;
                float w11 = wy * wx * m11;
                int cy0 = min(max(y0, 0), HH - 1), cy1 = min(max(y1, 0), HH - 1);
                int cx0 = min(max(x0, 0), WW - 1), cx1 = min(max(x1, 0), WW - 1);
                int ry0 = cy0 - ty0 + 4, ry1 = cy1 - ty0 + 4;
                int rx0 = cx0 - tx0 + 4, rx1 = cx1 - tx0 + 4;
                bool allin = ((unsigned)ry0 < 16u) & ((unsigned)ry1 < 16u) &
                             ((unsigned)rx0 < 16u) & ((unsigned)rx1 < 16u);
                const int qc = gl << 1;       // first channel-quad of this group
                floatx4 a0, b0, c0, d0, a1, b1, c1, d1;
                if (allin) {
                    int s00 = (ry0 << 4) + rx0, s01 = (ry0 << 4) + rx1;
                    int s10 = (ry1 << 4) + rx0, s11 = (ry1 << 4) + rx1;
                    int m0 = (s00 >> 1) & 3, m1 = (s01 >> 1) & 3;
                    int m2 = (s10 >> 1) & 3, m3 = (s11 >> 1) & 3;
                    a0 = *(const floatx4*)&stg[(s00 << 4) + ((qc ^ m0) << 2)];
                    a1 = *(const floatx4*)&stg[(s00 << 4) + (((qc + 1) ^ m0) << 2)];
                    b0 = *(const floatx4*)&stg[(s01 << 4) + ((qc ^ m1) << 2)];
                    b1 = *(const floatx4*)&stg[(s01 << 4) + (((qc + 1) ^ m1) << 2)];
                    c0 = *(const floatx4*)&stg[(s10 << 4) + ((qc ^ m2) << 2)];
                    c1 = *(const floatx4*)&stg[(s10 << 4) + (((qc + 1) ^ m2) << 2)];
                    d0 = *(const floatx4*)&stg[(s11 << 4) + ((qc ^ m3) << 2)];
                    d1 = *(const floatx4*)&stg[(s11 << 4) + (((qc + 1) ^ m3) << 2)];
                } else {
                    const int co = g * 8;
                    const float* p00 = ibase + (size_t)(cy0 * WW + cx0) * 64 + co;
                    const float* p01 = ibase + (size_t)(cy0 * WW + cx1) * 64 + co;
                    const float* p10 = ibase + (size_t)(cy1 * WW + cx0) * 64 + co;
                    const float* p11 = ibase + (size_t)(cy1 * WW + cx1) * 64 + co;
                    a0 = *(const floatx4*)p00;  a1 = *(const floatx4*)(p00 + 4);
                    b0 = *(const floatx4*)p01;  b1 = *(const floatx4*)(p01 + 4);
                    c0 = *(const floatx4*)p10;  c1 = *(const floatx4*)(p10 + 4);
                    d0 = *(const floatx4*)p11;  d1 = *(const floatx4*)(p11 + 4);
                }
                floatx4 sv0 = a0 * w00 + b0 * w01 + c0 * w10 + d0 * w11;
                floatx4 sv1 = a1 * w00 + b1 * w01 + c1 * w10 + d1 * w11;
                union { unsigned u[4]; _Float16 e[8]; } P, L;
#pragma unroll
                for (int j = 0; j < 4; ++j) {
                    _Float16 h0 = (_Float16)sv0[j];
                    _Float16 h1 = (_Float16)sv1[j];
                    P.e[j]     = h0;
                    P.e[j + 4] = h1;
                    L.e[j]     = (_Float16)(sv0[j] - (float)h0);
                    L.e[j + 4] = (_Float16)(sv1[j] - (float)h1);
                }
                int sb = px * SROW + gl * 72 + kk * 8;    // even -> 4-B aligned
                unsigned* shp = (unsigned*)&sh[sb];
                unsigned* slp = (unsigned*)&sl[sb];
                shp[0] = P.u[0]; shp[1] = P.u[1]; shp[2] = P.u[2]; shp[3] = P.u[3];
                slp[0] = L.u[0]; slp[1] = L.u[1]; slp[2] = L.u[2]; slp[3] = L.u[3];
            }
        }
        __syncthreads();
        // ---- phase B: MFMA contraction, wave w8 -> (co-tile q4, px-slots sb2..sb2+1)
#pragma unroll
        for (int kc5 = 0; kc5 < 5; ++kc5) {
            int kcg = r * 5 + kc5;
            size_t base = (size_t)((q4 * 20 + kcg) * 2) * 512;
            half8 Ah = *(const half8*)(wp + base + lane * 8);
            half8 Al = *(const half8*)(wp + base + 512 + lane * 8);
#pragma unroll
            for (int s = 0; s < 2; ++s) {
                int px = (sb2 + s) * 16 + n;
                const int ix = px * SROW + kc5 * 32 + quad * 8;
                half8 Bh = *(const half8*)&sh[ix];
                half8 Bl = *(const half8*)&sl[ix];
                acc[s] = __builtin_amdgcn_mfma_f32_16x16x32_f16(Ah, Bh, acc[s], 0, 0, 0);
                acc[s] = __builtin_amdgcn_mfma_f32_16x16x32_f16(Ah, Bl, acc[s], 0, 0, 0);
                acc[s] = __builtin_amdgcn_mfma_f32_16x16x32_f16(Al, Bh, acc[s], 0, 0, 0);
            }
        }
    }
    const floatx4 b4 = *(const floatx4*)(bias + q4 * 16 + quad * 4);
#pragma unroll
    for (int s = 0; s < 2; ++s) {
        int px = (sb2 + s) * 16 + n;
        int oy = ty0 + (px >> 3), ox = tx0 + (px & 7);
        float* op = out + ((size_t)jl * HWP + (size_t)oy * WW + ox) * 64
                        + q4 * 16 + quad * 4;
        *(floatx4*)op = acc[s] + b4;
    }
}

// rec conv (64 -> 3): fp32, channel-last input. Writes d_out (planar).
__global__ __launch_bounds__(256) void conv3x3_rec_k(
    const float* __restrict__ in, const float* __restrict__ w,
    const float* __restrict__ bias, float* __restrict__ out, int job0)
{
    constexpr int CB = 8;
    constexpr int PITCH = 48;
    constexpr int CH = 18 * PITCH;
    const int jl = blockIdx.y, jg = job0 + jl;
    const int b = jg & 1, fi = jg >> 1;
    const int frame = fi + (fi >= 2 ? 1 : 0);
    const int tile = blockIdx.x;
    const int ty0 = (tile >> 3) << 4, tx0 = (tile & 7) << 4;
    const int tid = threadIdx.x;
    const int tx = tid & 15, ty = tid >> 4;
    const float* srcA = in + (size_t)jl * NC * HWP;

    __shared__ float lds[CB * CH];
    float acc[3] = {bias[0], bias[1], bias[2]};

    for (int cb = 0; cb < NC; cb += CB) {
        __syncthreads();
        for (int e = tid; e < CB * 324; e += 256) {
            int c = e & 7;
            int r = e >> 3;
            int iy = r / 18, ix = r - iy * 18;
            int gy = ty0 - 1 + iy, gx = tx0 - 1 + ix;
            float v = 0.f;
            if (gy >= 0 && gy < HH && gx >= 0 && gx < WW)
                v = srcA[(size_t)(gy * WW + gx) * 64 + cb + c];
            lds[c * CH + iy * PITCH + ix] = v;
        }
        __syncthreads();
#pragma unroll
        for (int c = 0; c < CB; ++c) {
            float t[9];
#pragma unroll
            for (int dy = 0; dy < 3; ++dy)
#pragma unroll
                for (int dx = 0; dx < 3; ++dx)
                    t[dy * 3 + dx] = lds[c * CH + (ty + dy) * PITCH + (tx + dx)];
            int ci = cb + c;
#pragma unroll
            for (int o = 0; o < 3; ++o) {
                const float* wo = w + ((size_t)o * NC + ci) * 9;
#pragma unroll
                for (int kk = 0; kk < 9; ++kk)
                    acc[o] = fmaf(wo[kk], t[kk], acc[o]);
            }
        }
    }
    const int oy = ty0 + ty, ox = tx0 + tx;
#pragma unroll
    for (int o = 0; o < 3; ++o)
        out[((size_t)(b * NN + frame) * 3 + o) * HWP + oy * WW + ox] = acc[o];
}

extern "C" void kernel_launch(void* const* d_in, const int* in_sizes, int n_in,
                              void* d_out, int out_size, void* d_ws, size_t ws_size,
                              hipStream_t stream)
{
    const float* pf    = (const float*)d_in[0];
    const float* xc    = (const float*)d_in[1];
    const float* cr_w  = (const float*)d_in[2];
    const float* cr_b  = (const float*)d_in[3];
    const float* ow[4] = {(const float*)d_in[4],  (const float*)d_in[8],
                          (const float*)d_in[12], (const float*)d_in[16]};
    const float* ob[4] = {(const float*)d_in[5],  (const float*)d_in[9],
                          (const float*)d_in[13], (const float*)d_in[17]};
    const float* dw[4] = {(const float*)d_in[6],  (const float*)d_in[10],
                          (const float*)d_in[14], (const float*)d_in[18]};
    const float* db[4] = {(const float*)d_in[7],  (const float*)d_in[11],
                          (const float*)d_in[15], (const float*)d_in[19]};
    const float* rec_w = (const float*)d_in[20];
    const float* rec_b = (const float*)d_in[21];
    float* out = (float*)d_out;

    // ws layout: [wp cr x2][wp of x4][wp dc x4][R 2][S JC][A JC][Bb JC][O JC]
    const size_t WPC = (size_t)4 * NKC * 1024;
    const size_t WPO = (size_t)9 * NKC * 1024;
    const size_t WPD = (size_t)4 * 20 * 1024;
    _Float16* wp_cr0 = (_Float16*)d_ws;
    _Float16* wp_cr1 = wp_cr0 + WPC;
    _Float16* wp_of[4];
    _Float16* wp_dc[4];
    _Float16* curh = wp_cr1 + WPC;
    for (int i = 0; i < 4; ++i) { wp_of[i] = curh; curh += WPO; }
    for (int i = 0; i < 4; ++i) { wp_dc[i] = curh; curh += WPD; }
    size_t wp_bytes = (size_t)((char*)curh - (char*)d_ws);

    const size_t fplane = (size_t)NC * HWP;
    const size_t oplane = (size_t)OFFC * HWP;
    int JC = 8;
    while (JC > 1 &&
           wp_bytes + (2 + 3 * (size_t)JC) * fplane * 4 + (size_t)JC * oplane * 4 > ws_size)
        JC >>= 1;
    float* R  = (float*)curh;
    float* S  = R  + 2 * fplane;
    float* A  = S  + (size_t)JC * fplane;
    float* Bb = A  + (size_t)JC * fplane;
    float* O  = Bb + (size_t)JC * fplane;

    // ---- weight preprocessing + ref repack (every call; ws re-poisoned) ----
    {
        int nc4 = 4 * NKC * 64, nc9 = 9 * NKC * 64, ncd = 4 * 20 * 64;
        dim3 b4((nc4 + 255) / 256), b9((nc9 + 255) / 256), bd((ncd + 255) / 256);
        prew_k<<<b4, 256, 0, stream>>>(cr_w, wp_cr0, 4, NKC, 0, 0, 128);
        prew_k<<<b4, 256, 0, stream>>>(cr_w, wp_cr1, 4, NKC, 0, 64, 128);
        for (int i = 0; i < 4; ++i) {
            prew_k<<<b9, 256, 0, stream>>>(ow[i], wp_of[i], 9, NKC, 0, 0, 64);
            prew_k<<<bd, 256, 0, stream>>>(dw[i], wp_dc[i], 4, 20, 1, 0, 64);
        }
        repack_k<<<dim3(256, 2), 256, 0, stream>>>(pf, R, 0, 1);
    }

    copy_center_k<<<dim3((NB * 3 * HWP + 255) / 256), 256, 0, stream>>>(xc, out);

    for (int job0 = 0; job0 < 8; job0 += JC) {
        dim3 blk(256);
        dim3 blk512(512);
        dim3 gconv(128, JC), gdef(256, JC), grec(64, JC);
        repack_k<<<dim3(256, JC), blk, 0, stream>>>(pf, S, job0, 0);
        // fea1 = cr_conv(concat(ref, supp)) : FUSED single pass (R25)
        mcrconv_k<<<gconv, blk, 0, stream>>>(R, S, wp_cr0, wp_cr1, cr_b, A, job0);
        // off1(fea1); fea2 = deform(fea1)
        mconv_k<9, 0, 0><<<gconv, blk, 0, stream>>>(A, R, S, wp_of[0], ob[0], O, job0);
        mdeform_k<<<gdef, blk512, 0, stream>>>(A, O, wp_dc[0], db[0], Bb, 0, S);
        // off2(fea2); fea3 = deform(fea2)
        mconv_k<9, 0, 0><<<gconv, blk, 0, stream>>>(Bb, R, S, wp_of[1], ob[1], O, job0);
        mdeform_k<<<gdef, blk512, 0, stream>>>(Bb, O, wp_dc[1], db[1], A, 0, S);
        // off3(fea3); fea4 = deform(supp)
        mconv_k<9, 0, 0><<<gconv, blk, 0, stream>>>(A, R, S, wp_of[2], ob[2], O, job0);
        mdeform_k<<<gdef, blk512, 0, stream>>>(nullptr, O, wp_dc[2], db[2], Bb, 1, S);
        // off4(fea4); aligned = deform(fea4)
        mconv_k<9, 0, 0><<<gconv, blk, 0, stream>>>(Bb, R, S, wp_of[3], ob[3], O, job0);
        mdeform_k<<<gdef, blk512, 0, stream>>>(Bb, O, wp_dc[3], db[3], A, 0, S);
        // out[b, frame] = rec_conv(aligned)
        conv3x3_rec_k<<<grec, blk, 0, stream>>>(A, rec_w, rec_b, out, job0);
    }
}

// Round 15
// 1073.982 us; speedup vs baseline: 1.0096x; 1.0096x over previous
//
#include <hip/hip_runtime.h>

#define HH 128
#define WW 128
#define HWP (HH*WW)
#define NC 64
#define NB 2
#define NN 5
#define OFFC 144
#define NKC 18                    // K-chunks of 32 per 576-K conv pass

typedef __attribute__((ext_vector_type(8))) _Float16 half8;
typedef __attribute__((ext_vector_type(4))) float floatx4;
typedef __attribute__((ext_vector_type(2))) float floatx2;

// out[b, center=2] = x_center
__global__ __launch_bounds__(256) void copy_center_k(const float* __restrict__ xc,
                                                     float* __restrict__ out) {
    int idx = blockIdx.x * 256 + threadIdx.x;
    const int total = NB * 3 * HWP;
    if (idx >= total) return;
    int b = idx / (3 * HWP);
    int r = idx - b * 3 * HWP;
    out[(size_t)((b * NN + 2) * 3) * HWP + r] = xc[idx];
}

// Repack planar pf frame -> channel-last [px][64]. is_ref: blockIdx.y = b (center frame);
// else blockIdx.y = jl (supp frame of job job0+jl). LDS 64x65 transpose tile.
__global__ __launch_bounds__(256) void repack_k(const float* __restrict__ pf,
                                                float* __restrict__ dst, int job0, int is_ref)
{
    __shared__ float T[64][65];
    const int jl = blockIdx.y;
    const float* src;
    if (is_ref) {
        src = pf + (size_t)((jl * NN + 2) * NC) * HWP;
    } else {
        int jg = job0 + jl;
        int b = jg & 1, fi = jg >> 1;
        int frame = fi + (fi >= 2 ? 1 : 0);
        src = pf + (size_t)((b * NN + frame) * NC) * HWP;
    }
    float* d = dst + (size_t)jl * NC * HWP;
    const int p0 = blockIdx.x * 64;
    const int tid = threadIdx.x;
    const int lx = tid & 63, cg4 = tid >> 6;
#pragma unroll
    for (int cc = 0; cc < 16; ++cc) {
        int c = cc * 4 + cg4;
        T[c][lx] = src[(size_t)c * HWP + p0 + lx];
    }
    __syncthreads();
    const int px = tid >> 2, c0 = (tid & 3) * 16;
#pragma unroll
    for (int j = 0; j < 4; ++j) {
        floatx4 v = { T[c0 + j*4 + 0][px], T[c0 + j*4 + 1][px],
                      T[c0 + j*4 + 2][px], T[c0 + j*4 + 3][px] };
        *(floatx4*)(d + (size_t)(p0 + px) * 64 + c0 + j*4) = v;
    }
}

// Weight preprocessor, SPLIT-fp16: w[co][cin_src][9] -> wp[ct][kc][{hi,lo}][lane][8],
// k = kc*32 + (lane>>4)*8 + j.
// mode 0 (conv, nkc=18):   kk = k>>6, ci = k&63 (+ci_off).
// mode 1 (deform, nkc=20): r = k/160, kr = k%160; kr<144: g = r*2 + kr/72,
//                          kk = (kr%72)>>3, cg = kr&7, ci = g*8+cg; else zero pad.
__global__ __launch_bounds__(256) void prew_k(const float* __restrict__ w,
                                              _Float16* __restrict__ wp,
                                              int nct, int nkc, int mode,
                                              int ci_off, int cin_src)
{
    int idx = blockIdx.x * 256 + threadIdx.x;
    if (idx >= nct * nkc * 64) return;
    int lane = idx & 63;
    int kc = (idx >> 6) % nkc;
    int ct = (idx >> 6) / nkc;
    int m = lane & 15, quad = lane >> 4;
    int co = ct * 16 + m;
    union { half8 v; _Float16 e[8]; } ph, pl;
#pragma unroll
    for (int j = 0; j < 8; ++j) {
        int k = kc * 32 + quad * 8 + j;
        float f = 0.f;
        if (mode == 0) {
            int kk = k >> 6, ci = k & 63;
            f = w[((size_t)co * cin_src + ci_off + ci) * 9 + kk];
        } else {
            int r = k / 160, kr = k - r * 160;
            if (kr < 144) {
                int g = r * 2 + kr / 72;
                int rr = kr % 72;
                int kk = rr >> 3, cg = rr & 7;
                f = w[((size_t)co * cin_src + g * 8 + cg) * 9 + kk];
            }
        }
        _Float16 h = (_Float16)f;
        ph.e[j] = h; pl.e[j] = (_Float16)(f - (float)h);
    }
    size_t base = (size_t)((ct * nkc + kc) * 2) * 512;
    *(half8*)(wp + base + lane * 8) = ph.v;
    *(half8*)(wp + base + 512 + lane * 8) = pl.v;
}

// SPLIT-fp16 MFMA 3x3 conv, CHANNEL-LAST src & dst. R16 structure + R18
// A-BATCH HOIST + R22 DEPTH-1 A-PIPELINE (proven: mconv9 dropped below the
// mdeform line). Two named A-register sets (E/O), kc unrolled 2x; every
// A-batch issues a full MFMA-block before first use.
template<int NCT, int SRCMODE, int ADD>
__global__ __launch_bounds__(256, 2) void mconv_k(
    const float* __restrict__ src, const float* __restrict__ R,
    const float* __restrict__ S, const _Float16* __restrict__ wp,
    const float* __restrict__ bias, float* __restrict__ out, int job0)
{
    constexpr int PL = 1456;              // 10*18*8 = 1440 + 16 pad (fp16 elems)
    constexpr int Ct = NCT * 16;
    const int jl = blockIdx.y, jg = job0 + jl;
    const int b = jg & 1;
    const int tile = blockIdx.x;          // 8 in x, 16 in y
    const int ty0 = (tile >> 3) << 3, tx0 = (tile & 7) << 4;
    const int tid = threadIdx.x;
    const int lane = tid & 63;
    const int wq = __builtin_amdgcn_readfirstlane(tid >> 6);
    const int n = lane & 15, quad = lane >> 4;

    const float* s0;
    if (SRCMODE == 0)      s0 = src + (size_t)jl * NC * HWP;
    else if (SRCMODE == 1) s0 = R + (size_t)b * NC * HWP;
    else                   s0 = S + (size_t)jl * NC * HWP;

    __shared__ _Float16 hh[8 * PL];
    __shared__ _Float16 ll[8 * PL];

    for (int t = tid; t < 360; t += 256) {
        int px = t >> 1, hf = t & 1;
        int hy = px / 18, hx = px - hy * 18;
        int gy = ty0 - 1 + hy, gx = tx0 - 1 + hx;
        bool ok = (gy >= 0 && gy < HH && gx >= 0 && gx < WW);
        const float* sp = s0 + (ok ? ((size_t)(gy * WW + gx) * 64) : 0) + hf * 32;
        int lb = px * 8;
#pragma unroll
        for (int c = 0; c < 4; ++c) {
            int cb = hf * 4 + c;
            floatx4 f0 = {0.f,0.f,0.f,0.f}, f1 = {0.f,0.f,0.f,0.f};
            if (ok) {
                f0 = *(const floatx4*)(sp + c * 8);
                f1 = *(const floatx4*)(sp + c * 8 + 4);
            }
            union { half8 v; _Float16 e[8]; } ph, pl;
#pragma unroll
            for (int j = 0; j < 4; ++j) {
                _Float16 h0 = (_Float16)f0[j], h1 = (_Float16)f1[j];
                ph.e[j] = h0;     ph.e[j+4] = h1;
                pl.e[j] = (_Float16)(f0[j] - (float)h0);
                pl.e[j+4] = (_Float16)(f1[j] - (float)h1);
            }
            *(half8*)&hh[cb * PL + lb] = ph.v;
            *(half8*)&ll[cb * PL + lb] = pl.v;
        }
    }
    __syncthreads();

    floatx4 acc0[NCT], acc1[NCT];
#pragma unroll
    for (int ct = 0; ct < NCT; ++ct) {
        acc0[ct] = floatx4{0.f, 0.f, 0.f, 0.f};
        acc1[ct] = floatx4{0.f, 0.f, 0.f, 0.f};
    }
    const int y0 = wq * 2, y1 = y0 + 1;

    half8 AhE[NCT], AlE[NCT], AhO[NCT], AlO[NCT];
    // prologue: A-batch for kc=0 into E
    {
        const _Float16* wk0 = wp + lane * 8;
#pragma unroll
        for (int ct = 0; ct < NCT; ++ct) {
            const _Float16* wc = wk0 + (size_t)ct * NKC * 1024;
            AhE[ct] = *(const half8*)wc;
            AlE[ct] = *(const half8*)(wc + 512);
        }
    }
#pragma unroll
    for (int kc2 = 0; kc2 < NKC; kc2 += 2) {
        // ---- even kc = kc2: prefetch O = A(kc2+1), MFMA from E ----
        {
            const int kc = kc2;
            const _Float16* wkn = wp + (size_t)(kc + 1) * 1024 + lane * 8;
#pragma unroll
            for (int ct = 0; ct < NCT; ++ct) {
                const _Float16* wc = wkn + (size_t)ct * NKC * 1024;
                AhO[ct] = *(const half8*)wc;
                AlO[ct] = *(const half8*)(wc + 512);
            }
            const int kk = kc >> 1;
            const int dy = kk / 3, dx = kk % 3;
            const int cb = ((kc & 1) << 2) + quad;
            const int ix0 = cb * PL + ((y0 + dy) * 18 + n + dx) * 8;
            const int ix1 = cb * PL + ((y1 + dy) * 18 + n + dx) * 8;
            half8 B0h = *(const half8*)&hh[ix0];
            half8 B0l = *(const half8*)&ll[ix0];
            half8 B1h = *(const half8*)&hh[ix1];
            half8 B1l = *(const half8*)&ll[ix1];
#pragma unroll
            for (int ct = 0; ct < NCT; ++ct) {
                acc0[ct] = __builtin_amdgcn_mfma_f32_16x16x32_f16(AhE[ct], B0h, acc0[ct], 0, 0, 0);
                acc0[ct] = __builtin_amdgcn_mfma_f32_16x16x32_f16(AhE[ct], B0l, acc0[ct], 0, 0, 0);
                acc0[ct] = __builtin_amdgcn_mfma_f32_16x16x32_f16(AlE[ct], B0h, acc0[ct], 0, 0, 0);
                acc1[ct] = __builtin_amdgcn_mfma_f32_16x16x32_f16(AhE[ct], B1h, acc1[ct], 0, 0, 0);
                acc1[ct] = __builtin_amdgcn_mfma_f32_16x16x32_f16(AhE[ct], B1l, acc1[ct], 0, 0, 0);
                acc1[ct] = __builtin_amdgcn_mfma_f32_16x16x32_f16(AlE[ct], B1h, acc1[ct], 0, 0, 0);
            }
        }
        // ---- odd kc = kc2+1: prefetch E = A(kc2+2) (if any), MFMA from O ----
        {
            const int kc = kc2 + 1;
            if (kc2 + 2 < NKC) {
                const _Float16* wkn = wp + (size_t)(kc2 + 2) * 1024 + lane * 8;
#pragma unroll
                for (int ct = 0; ct < NCT; ++ct) {
                    const _Float16* wc = wkn + (size_t)ct * NKC * 1024;
                    AhE[ct] = *(const half8*)wc;
                    AlE[ct] = *(const half8*)(wc + 512);
                }
            }
            const int kk = kc >> 1;
            const int dy = kk / 3, dx = kk % 3;
            const int cb = ((kc & 1) << 2) + quad;
            const int ix0 = cb * PL + ((y0 + dy) * 18 + n + dx) * 8;
            const int ix1 = cb * PL + ((y1 + dy) * 18 + n + dx) * 8;
            half8 B0h = *(const half8*)&hh[ix0];
            half8 B0l = *(const half8*)&ll[ix0];
            half8 B1h = *(const half8*)&hh[ix1];
            half8 B1l = *(const half8*)&ll[ix1];
#pragma unroll
            for (int ct = 0; ct < NCT; ++ct) {
                acc0[ct] = __builtin_amdgcn_mfma_f32_16x16x32_f16(AhO[ct], B0h, acc0[ct], 0, 0, 0);
                acc0[ct] = __builtin_amdgcn_mfma_f32_16x16x32_f16(AhO[ct], B0l, acc0[ct], 0, 0, 0);
                acc0[ct] = __builtin_amdgcn_mfma_f32_16x16x32_f16(AlO[ct], B0h, acc0[ct], 0, 0, 0);
                acc1[ct] = __builtin_amdgcn_mfma_f32_16x16x32_f16(AhO[ct], B1h, acc1[ct], 0, 0, 0);
                acc1[ct] = __builtin_amdgcn_mfma_f32_16x16x32_f16(AhO[ct], B1l, acc1[ct], 0, 0, 0);
                acc1[ct] = __builtin_amdgcn_mfma_f32_16x16x32_f16(AlO[ct], B1h, acc1[ct], 0, 0, 0);
            }
        }
    }

    const int oy0 = ty0 + y0, oy1 = ty0 + y1, ox = tx0 + n;
#pragma unroll
    for (int ct = 0; ct < NCT; ++ct) {
        const floatx4 b4 = *(const floatx4*)(bias + ct * 16 + quad * 4);
        float* op0 = out + ((size_t)jl * HWP + (size_t)oy0 * WW + ox) * Ct
                         + ct * 16 + quad * 4;
        float* op1 = out + ((size_t)jl * HWP + (size_t)oy1 * WW + ox) * Ct
                         + ct * 16 + quad * 4;
        floatx4 v0 = acc0[ct], v1 = acc1[ct];
        if (ADD) {
            v0 += *(const floatx4*)op0;
            v1 += *(const floatx4*)op1;
        } else {
            v0 += b4;
            v1 += b4;
        }
        *(floatx4*)op0 = v0;
        *(floatx4*)op1 = v1;
    }
}

// Deformable conv, MFMA phase B (split-fp16). CHANNEL-LAST.
// R16: LDS-STAGED GATHER (proven). R19: de-paired phase A (proven).
// R21: offset prefetch + unrolled phase A (proven). Final session state:
// structural floor for this decomposition — gather-transaction + LDS-
// conflict bound, all pipes <40%, four restructures (R14/R17/R20/R23)
// regressed against it.
__global__ __launch_bounds__(512, 4) void mdeform_k(
    const float* __restrict__ in, const float* __restrict__ off,
    const _Float16* __restrict__ wp, const float* __restrict__ bias,
    float* __restrict__ out, int supp_mode, const float* __restrict__ S)
{
    constexpr int SROW = 166;
    const int jl = blockIdx.y;
    const int tile = blockIdx.x;          // 16x16 tiles of 8x8
    const int ty0 = (tile >> 4) << 3, tx0 = (tile & 15) << 3;
    const int tid = threadIdx.x;
    const int lane = tid & 63;
    const int w8 = __builtin_amdgcn_readfirstlane(tid >> 6);  // wave 0..7
    const int q4 = w8 >> 1;               // co-tile 0..3
    const int sb2 = (w8 & 1) << 1;        // px-slot base: 0 or 2
    const int n = lane & 15, quad = lane >> 4;

    const float* ibase = supp_mode ? (S + (size_t)jl * NC * HWP)
                                   : (in + (size_t)jl * NC * HWP);
    const float* obase = off + (size_t)jl * OFFC * HWP;

    __shared__ _Float16 sh[64 * SROW];
    __shared__ _Float16 sl[64 * SROW];
    __shared__ float stg[256 * 16];       // 16x16 region x 16ch, quad-swizzled

    // zero pad K-slots [144,160)
    for (int e = tid; e < 64 * 16; e += 512) {
        int row = e >> 4, col = 144 + (e & 15);
        sh[row * SROW + col] = (_Float16)0.f;
        sl[row * SROW + col] = (_Float16)0.f;
    }

    floatx4 acc[2];
#pragma unroll
    for (int s = 0; s < 2; ++s) acc[s] = floatx4{0.f, 0.f, 0.f, 0.f};

    for (int r = 0; r < 4; ++r) {
        // ---- R21: prefetch this r's offsets (independent global loads; their
        // latency drains under the staging wait + barrier below)
        floatx2 o2v[3];
#pragma unroll
        for (int i = 0; i < 3; ++i) {
            int idx = tid + (i << 9);
            if (idx < 1152) {
                int gl = idx / 576;
                int rem = idx - gl * 576;
                int kk = rem >> 6;
                int px = rem & 63;
                int g = r * 2 + gl;
                int yy = ty0 + (px >> 3), xx = tx0 + (px & 7);
                o2v[i] = *(const floatx2*)(obase + (size_t)(yy * WW + xx) * OFFC
                                           + (g * 9 + kk) * 2);
            }
        }
        // ---- stage input region for this r's 16 channels (overlaps prev phase B)
#pragma unroll
        for (int j = 0; j < 2; ++j) {
            int t = tid + (j << 9);           // 0..1023
            int slot = t >> 2;                // 0..255 = ry*16+rx
            int qq = t & 3;
            int ry = slot >> 4, rx = slot & 15;
            int gy = ty0 - 4 + ry, gx = tx0 - 4 + rx;
            if ((unsigned)gy < (unsigned)HH && (unsigned)gx < (unsigned)WW) {
                floatx4 v = *(const floatx4*)(ibase + (size_t)(gy * WW + gx) * 64
                                              + r * 16 + qq * 4);
                *(floatx4*)&stg[(slot << 4) + ((qq ^ ((slot >> 1) & 3)) << 2)] = v;
            }
        }
        __syncthreads();   // staging visible; prev phase B done reading sh/sl
        // ---- phase A: de-paired tasks, UNROLLED. 1152 = 2(gl) x 9(kk) x 64(px)
#pragma unroll
        for (int i = 0; i < 3; ++i) {
            int idx = tid + (i << 9);         // 0..1535, active < 1152
            if (idx < 1152) {
                int gl = idx / 576;
                int rem = idx - gl * 576;
                int kk = rem >> 6;
                int px = rem & 63;
                int g = r * 2 + gl;
                int yy = ty0 + (px >> 3), xx = tx0 + (px & 7);
                floatx2 o2 = o2v[i];
                float pyf = (float)(yy + (kk / 3) - 1) + o2[0];
                float pxf = (float)(xx + (kk % 3) - 1) + o2[1];
                float fy = floorf(pyf), fx = floorf(pxf);
                float wy = pyf - fy, wx = pxf - fx;
                int y0 = (int)fy, x0 = (int)fx;
                int y1 = y0 + 1, x1 = x0 + 1;
                float m00 = (y0 >= 0 && y0 < HH && x0 >= 0 && x0 < WW) ? 1.f : 0.f;
                float m01 = (y0 >= 0 && y0 < HH && x1 >= 0 && x1 < WW) ? 1.f : 0.f;
                float m10 = (y1 >= 0 && y1 < HH && x0 >= 0 && x0 < WW) ? 1.f : 0.f;
                float m11 = (y1 >= 0 && y1 < HH && x1 >= 0 && x1 < WW) ? 1.f : 0.f;
                float w00 = (1.f - wy) * (1.f - wx) * m00;
                float w01 = (1.f - wy) * wx * m01;
                float w10 = wy * (1.f - wx) * m10;
                float w11 = wy * wx * m11;
                int cy0 = min(max(y0, 0), HH - 1), cy1 = min(max(y1, 0), HH - 1);
                int cx0 = min(max(x0, 0), WW - 1), cx1 = min(max(x1, 0), WW - 1);
                int ry0 = cy0 - ty0 + 4, ry1 = cy1 - ty0 + 4;
                int rx0 = cx0 - tx0 + 4, rx1 = cx1 - tx0 + 4;
                bool allin = ((unsigned)ry0 < 16u) & ((unsigned)ry1 < 16u) &
                             ((unsigned)rx0 < 16u) & ((unsigned)rx1 < 16u);
                const int qc = gl << 1;       // first channel-quad of this group
                floatx4 a0, b0, c0, d0, a1, b1, c1, d1;
                if (allin) {
                    int s00 = (ry0 << 4) + rx0, s01 = (ry0 << 4) + rx1;
                    int s10 = (ry1 << 4) + rx0, s11 = (ry1 << 4) + rx1;
                    int m0 = (s00 >> 1) & 3, m1 = (s01 >> 1) & 3;
                    int m2 = (s10 >> 1) & 3, m3 = (s11 >> 1) & 3;
                    a0 = *(const floatx4*)&stg[(s00 << 4) + ((qc ^ m0) << 2)];
                    a1 = *(const floatx4*)&stg[(s00 << 4) + (((qc + 1) ^ m0) << 2)];
                    b0 = *(const floatx4*)&stg[(s01 << 4) + ((qc ^ m1) << 2)];
                    b1 = *(const floatx4*)&stg[(s01 << 4) + (((qc + 1) ^ m1) << 2)];
                    c0 = *(const floatx4*)&stg[(s10 << 4) + ((qc ^ m2) << 2)];
                    c1 = *(const floatx4*)&stg[(s10 << 4) + (((qc + 1) ^ m2) << 2)];
                    d0 = *(const floatx4*)&stg[(s11 << 4) + ((qc ^ m3) << 2)];
                    d1 = *(const floatx4*)&stg[(s11 << 4) + (((qc + 1) ^ m3) << 2)];
                } else {
                    const int co = g * 8;
                    const float* p00 = ibase + (size_t)(cy0 * WW + cx0) * 64 + co;
                    const float* p01 = ibase + (size_t)(cy0 * WW + cx1) * 64 + co;
                    const float* p10 = ibase + (size_t)(cy1 * WW + cx0) * 64 + co;
                    const float* p11 = ibase + (size_t)(cy1 * WW + cx1) * 64 + co;
                    a0 = *(const floatx4*)p00;  a1 = *(const floatx4*)(p00 + 4);
                    b0 = *(const floatx4*)p01;  b1 = *(const floatx4*)(p01 + 4);
                    c0 = *(const floatx4*)p10;  c1 = *(const floatx4*)(p10 + 4);
                    d0 = *(const floatx4*)p11;  d1 = *(const floatx4*)(p11 + 4);
                }
                floatx4 sv0 = a0 * w00 + b0 * w01 + c0 * w10 + d0 * w11;
                floatx4 sv1 = a1 * w00 + b1 * w01 + c1 * w10 + d1 * w11;
                union { unsigned u[4]; _Float16 e[8]; } P, L;
#pragma unroll
                for (int j = 0; j < 4; ++j) {
                    _Float16 h0 = (_Float16)sv0[j];
                    _Float16 h1 = (_Float16)sv1[j];
                    P.e[j]     = h0;
                    P.e[j + 4] = h1;
                    L.e[j]     = (_Float16)(sv0[j] - (float)h0);
                    L.e[j + 4] = (_Float16)(sv1[j] - (float)h1);
                }
                int sb = px * SROW + gl * 72 + kk * 8;    // even -> 4-B aligned
                unsigned* shp = (unsigned*)&sh[sb];
                unsigned* slp = (unsigned*)&sl[sb];
                shp[0] = P.u[0]; shp[1] = P.u[1]; shp[2] = P.u[2]; shp[3] = P.u[3];
                slp[0] = L.u[0]; slp[1] = L.u[1]; slp[2] = L.u[2]; slp[3] = L.u[3];
            }
        }
        __syncthreads();
        // ---- phase B: MFMA contraction, wave w8 -> (co-tile q4, px-slots sb2..sb2+1)
#pragma unroll
        for (int kc5 = 0; kc5 < 5; ++kc5) {
            int kcg = r * 5 + kc5;
            size_t base = (size_t)((q4 * 20 + kcg) * 2) * 512;
            half8 Ah = *(const half8*)(wp + base + lane * 8);
            half8 Al = *(const half8*)(wp + base + 512 + lane * 8);
#pragma unroll
            for (int s = 0; s < 2; ++s) {
                int px = (sb2 + s) * 16 + n;
                const int ix = px * SROW + kc5 * 32 + quad * 8;
                half8 Bh = *(const half8*)&sh[ix];
                half8 Bl = *(const half8*)&sl[ix];
                acc[s] = __builtin_amdgcn_mfma_f32_16x16x32_f16(Ah, Bh, acc[s], 0, 0, 0);
                acc[s] = __builtin_amdgcn_mfma_f32_16x16x32_f16(Ah, Bl, acc[s], 0, 0, 0);
                acc[s] = __builtin_amdgcn_mfma_f32_16x16x32_f16(Al, Bh, acc[s], 0, 0, 0);
            }
        }
    }
    const floatx4 b4 = *(const floatx4*)(bias + q4 * 16 + quad * 4);
#pragma unroll
    for (int s = 0; s < 2; ++s) {
        int px = (sb2 + s) * 16 + n;
        int oy = ty0 + (px >> 3), ox = tx0 + (px & 7);
        float* op = out + ((size_t)jl * HWP + (size_t)oy * WW + ox) * 64
                        + q4 * 16 + quad * 4;
        *(floatx4*)op = acc[s] + b4;
    }
}

// rec conv (64 -> 3): fp32, channel-last input. Writes d_out (planar).
__global__ __launch_bounds__(256) void conv3x3_rec_k(
    const float* __restrict__ in, const float* __restrict__ w,
    const float* __restrict__ bias, float* __restrict__ out, int job0)
{
    constexpr int CB = 8;
    constexpr int PITCH = 48;
    constexpr int CH = 18 * PITCH;
    const int jl = blockIdx.y, jg = job0 + jl;
    const int b = jg & 1, fi = jg >> 1;
    const int frame = fi + (fi >= 2 ? 1 : 0);
    const int tile = blockIdx.x;
    const int ty0 = (tile >> 3) << 4, tx0 = (tile & 7) << 4;
    const int tid = threadIdx.x;
    const int tx = tid & 15, ty = tid >> 4;
    const float* srcA = in + (size_t)jl * NC * HWP;

    __shared__ float lds[CB * CH];
    float acc[3] = {bias[0], bias[1], bias[2]};

    for (int cb = 0; cb < NC; cb += CB) {
        __syncthreads();
        for (int e = tid; e < CB * 324; e += 256) {
            int c = e & 7;
            int r = e >> 3;
            int iy = r / 18, ix = r - iy * 18;
            int gy = ty0 - 1 + iy, gx = tx0 - 1 + ix;
            float v = 0.f;
            if (gy >= 0 && gy < HH && gx >= 0 && gx < WW)
                v = srcA[(size_t)(gy * WW + gx) * 64 + cb + c];
            lds[c * CH + iy * PITCH + ix] = v;
        }
        __syncthreads();
#pragma unroll
        for (int c = 0; c < CB; ++c) {
            float t[9];
#pragma unroll
            for (int dy = 0; dy < 3; ++dy)
#pragma unroll
                for (int dx = 0; dx < 3; ++dx)
                    t[dy * 3 + dx] = lds[c * CH + (ty + dy) * PITCH + (tx + dx)];
            int ci = cb + c;
#pragma unroll
            for (int o = 0; o < 3; ++o) {
                const float* wo = w + ((size_t)o * NC + ci) * 9;
#pragma unroll
                for (int kk = 0; kk < 9; ++kk)
                    acc[o] = fmaf(wo[kk], t[kk], acc[o]);
            }
        }
    }
    const int oy = ty0 + ty, ox = tx0 + tx;
#pragma unroll
    for (int o = 0; o < 3; ++o)
        out[((size_t)(b * NN + frame) * 3 + o) * HWP + oy * WW + ox] = acc[o];
}

extern "C" void kernel_launch(void* const* d_in, const int* in_sizes, int n_in,
                              void* d_out, int out_size, void* d_ws, size_t ws_size,
                              hipStream_t stream)
{
    const float* pf    = (const float*)d_in[0];
    const float* xc    = (const float*)d_in[1];
    const float* cr_w  = (const float*)d_in[2];
    const float* cr_b  = (const float*)d_in[3];
    const float* ow[4] = {(const float*)d_in[4],  (const float*)d_in[8],
                          (const float*)d_in[12], (const float*)d_in[16]};
    const float* ob[4] = {(const float*)d_in[5],  (const float*)d_in[9],
                          (const float*)d_in[13], (const float*)d_in[17]};
    const float* dw[4] = {(const float*)d_in[6],  (const float*)d_in[10],
                          (const float*)d_in[14], (const float*)d_in[18]};
    const float* db[4] = {(const float*)d_in[7],  (const float*)d_in[11],
                          (const float*)d_in[15], (const float*)d_in[19]};
    const float* rec_w = (const float*)d_in[20];
    const float* rec_b = (const float*)d_in[21];
    float* out = (float*)d_out;

    // ws layout: [wp cr x2][wp of x4][wp dc x4][R 2][S JC][A JC][Bb JC][O JC]
    const size_t WPC = (size_t)4 * NKC * 1024;
    const size_t WPO = (size_t)9 * NKC * 1024;
    const size_t WPD = (size_t)4 * 20 * 1024;
    _Float16* wp_cr0 = (_Float16*)d_ws;
    _Float16* wp_cr1 = wp_cr0 + WPC;
    _Float16* wp_of[4];
    _Float16* wp_dc[4];
    _Float16* curh = wp_cr1 + WPC;
    for (int i = 0; i < 4; ++i) { wp_of[i] = curh; curh += WPO; }
    for (int i = 0; i < 4; ++i) { wp_dc[i] = curh; curh += WPD; }
    size_t wp_bytes = (size_t)((char*)curh - (char*)d_ws);

    const size_t fplane = (size_t)NC * HWP;
    const size_t oplane = (size_t)OFFC * HWP;
    int JC = 8;
    while (JC > 1 &&
           wp_bytes + (2 + 3 * (size_t)JC) * fplane * 4 + (size_t)JC * oplane * 4 > ws_size)
        JC >>= 1;
    float* R  = (float*)curh;
    float* S  = R  + 2 * fplane;
    float* A  = S  + (size_t)JC * fplane;
    float* Bb = A  + (size_t)JC * fplane;
    float* O  = Bb + (size_t)JC * fplane;

    // ---- weight preprocessing + ref repack (every call; ws re-poisoned) ----
    {
        int nc4 = 4 * NKC * 64, nc9 = 9 * NKC * 64, ncd = 4 * 20 * 64;
        dim3 b4((nc4 + 255) / 256), b9((nc9 + 255) / 256), bd((ncd + 255) / 256);
        prew_k<<<b4, 256, 0, stream>>>(cr_w, wp_cr0, 4, NKC, 0, 0, 128);
        prew_k<<<b4, 256, 0, stream>>>(cr_w, wp_cr1, 4, NKC, 0, 64, 128);
        for (int i = 0; i < 4; ++i) {
            prew_k<<<b9, 256, 0, stream>>>(ow[i], wp_of[i], 9, NKC, 0, 0, 64);
            prew_k<<<bd, 256, 0, stream>>>(dw[i], wp_dc[i], 4, 20, 1, 0, 64);
        }
        repack_k<<<dim3(256, 2), 256, 0, stream>>>(pf, R, 0, 1);
    }

    copy_center_k<<<dim3((NB * 3 * HWP + 255) / 256), 256, 0, stream>>>(xc, out);

    for (int job0 = 0; job0 < 8; job0 += JC) {
        dim3 blk(256);
        dim3 blk512(512);
        dim3 gconv(128, JC), gdef(256, JC), grec(64, JC);
        repack_k<<<dim3(256, JC), blk, 0, stream>>>(pf, S, job0, 0);
        // fea1 = cr_conv(concat(ref, supp)) : two K=576 passes (ref, then supp ADD)
        mconv_k<4, 1, 0><<<gconv, blk, 0, stream>>>(nullptr, R, S, wp_cr0, cr_b, A, job0);
        mconv_k<4, 2, 1><<<gconv, blk, 0, stream>>>(nullptr, R, S, wp_cr1, cr_b, A, job0);
        // off1(fea1); fea2 = deform(fea1)
        mconv_k<9, 0, 0><<<gconv, blk, 0, stream>>>(A, R, S, wp_of[0], ob[0], O, job0);
        mdeform_k<<<gdef, blk512, 0, stream>>>(A, O, wp_dc[0], db[0], Bb, 0, S);
        // off2(fea2); fea3 = deform(fea2)
        mconv_k<9, 0, 0><<<gconv, blk, 0, stream>>>(Bb, R, S, wp_of[1], ob[1], O, job0);
        mdeform_k<<<gdef, blk512, 0, stream>>>(Bb, O, wp_dc[1], db[1], A, 0, S);
        // off3(fea3); fea4 = deform(supp)
        mconv_k<9, 0, 0><<<gconv, blk, 0, stream>>>(A, R, S, wp_of[2], ob[2], O, job0);
        mdeform_k<<<gdef, blk512, 0, stream>>>(nullptr, O, wp_dc[2], db[2], Bb, 1, S);
        // off4(fea4); aligned = deform(fea4)
        mconv_k<9, 0, 0><<<gconv, blk, 0, stream>>>(Bb, R, S, wp_of[3], ob[3], O, job0);
        mdeform_k<<<gdef, blk512, 0, stream>>>(Bb, O, wp_dc[3], db[3], A, 0, S);
        // out[b, frame] = rec_conv(aligned)
        conv3x3_rec_k<<<grec, blk, 0, stream>>>(A, rec_w, rec_b, out, job0);
    }
}

// Round 16
// 1073.877 us; speedup vs baseline: 1.0097x; 1.0001x over previous
//
#include <hip/hip_runtime.h>

#define HH 128
#define WW 128
#define HWP (HH*WW)
#define NC 64
#define NB 2
#define NN 5
#define OFFC 144
#define NKC 18                    // K-chunks of 32 per 576-K conv pass

typedef __attribute__((ext_vector_type(8))) _Float16 half8;
typedef __attribute__((ext_vector_type(4))) float floatx4;
typedef __attribute__((ext_vector_type(2))) float floatx2;

// out[b, center=2] = x_center
__global__ __launch_bounds__(256) void copy_center_k(const float* __restrict__ xc,
                                                     float* __restrict__ out) {
    int idx = blockIdx.x * 256 + threadIdx.x;
    const int total = NB * 3 * HWP;
    if (idx >= total) return;
    int b = idx / (3 * HWP);
    int r = idx - b * 3 * HWP;
    out[(size_t)((b * NN + 2) * 3) * HWP + r] = xc[idx];
}

// Repack planar pf frame -> channel-last [px][64]. is_ref: blockIdx.y = b (center frame);
// else blockIdx.y = jl (supp frame of job job0+jl). LDS 64x65 transpose tile.
__global__ __launch_bounds__(256) void repack_k(const float* __restrict__ pf,
                                                float* __restrict__ dst, int job0, int is_ref)
{
    __shared__ float T[64][65];
    const int jl = blockIdx.y;
    const float* src;
    if (is_ref) {
        src = pf + (size_t)((jl * NN + 2) * NC) * HWP;
    } else {
        int jg = job0 + jl;
        int b = jg & 1, fi = jg >> 1;
        int frame = fi + (fi >= 2 ? 1 : 0);
        src = pf + (size_t)((b * NN + frame) * NC) * HWP;
    }
    float* d = dst + (size_t)jl * NC * HWP;
    const int p0 = blockIdx.x * 64;
    const int tid = threadIdx.x;
    const int lx = tid & 63, cg4 = tid >> 6;
#pragma unroll
    for (int cc = 0; cc < 16; ++cc) {
        int c = cc * 4 + cg4;
        T[c][lx] = src[(size_t)c * HWP + p0 + lx];
    }
    __syncthreads();
    const int px = tid >> 2, c0 = (tid & 3) * 16;
#pragma unroll
    for (int j = 0; j < 4; ++j) {
        floatx4 v = { T[c0 + j*4 + 0][px], T[c0 + j*4 + 1][px],
                      T[c0 + j*4 + 2][px], T[c0 + j*4 + 3][px] };
        *(floatx4*)(d + (size_t)(p0 + px) * 64 + c0 + j*4) = v;
    }
}

// Weight preprocessor, SPLIT-fp16: w[co][cin_src][9] -> wp[ct][kc][{hi,lo}][lane][8],
// k = kc*32 + (lane>>4)*8 + j.
// mode 0 (conv, nkc=18):   kk = k>>6, ci = k&63 (+ci_off).
// mode 1 (deform, nkc=20): r = k/160, kr = k%160; kr<144: g = r*2 + kr/72,
//                          kk = (kr%72)>>3, cg = kr&7, ci = g*8+cg; else zero pad.
__global__ __launch_bounds__(256) void prew_k(const float* __restrict__ w,
                                              _Float16* __restrict__ wp,
                                              int nct, int nkc, int mode,
                                              int ci_off, int cin_src)
{
    int idx = blockIdx.x * 256 + threadIdx.x;
    if (idx >= nct * nkc * 64) return;
    int lane = idx & 63;
    int kc = (idx >> 6) % nkc;
    int ct = (idx >> 6) / nkc;
    int m = lane & 15, quad = lane >> 4;
    int co = ct * 16 + m;
    union { half8 v; _Float16 e[8]; } ph, pl;
#pragma unroll
    for (int j = 0; j < 8; ++j) {
        int k = kc * 32 + quad * 8 + j;
        float f = 0.f;
        if (mode == 0) {
            int kk = k >> 6, ci = k & 63;
            f = w[((size_t)co * cin_src + ci_off + ci) * 9 + kk];
        } else {
            int r = k / 160, kr = k - r * 160;
            if (kr < 144) {
                int g = r * 2 + kr / 72;
                int rr = kr % 72;
                int kk = rr >> 3, cg = rr & 7;
                f = w[((size_t)co * cin_src + g * 8 + cg) * 9 + kk];
            }
        }
        _Float16 h = (_Float16)f;
        ph.e[j] = h; pl.e[j] = (_Float16)(f - (float)h);
    }
    size_t base = (size_t)((ct * nkc + kc) * 2) * 512;
    *(half8*)(wp + base + lane * 8) = ph.v;
    *(half8*)(wp + base + 512 + lane * 8) = pl.v;
}

// SPLIT-fp16 MFMA 3x3 conv, CHANNEL-LAST src & dst. R16 structure + R18
// A-BATCH HOIST + R22 DEPTH-1 A-PIPELINE (proven: mconv9 dropped below the
// mdeform line). Two named A-register sets (E/O), kc unrolled 2x; every
// A-batch issues a full MFMA-block before first use.
template<int NCT, int SRCMODE, int ADD>
__global__ __launch_bounds__(256, 2) void mconv_k(
    const float* __restrict__ src, const float* __restrict__ R,
    const float* __restrict__ S, const _Float16* __restrict__ wp,
    const float* __restrict__ bias, float* __restrict__ out, int job0)
{
    constexpr int PL = 1456;              // 10*18*8 = 1440 + 16 pad (fp16 elems)
    constexpr int Ct = NCT * 16;
    const int jl = blockIdx.y, jg = job0 + jl;
    const int b = jg & 1;
    const int tile = blockIdx.x;          // 8 in x, 16 in y
    const int ty0 = (tile >> 3) << 3, tx0 = (tile & 7) << 4;
    const int tid = threadIdx.x;
    const int lane = tid & 63;
    const int wq = __builtin_amdgcn_readfirstlane(tid >> 6);
    const int n = lane & 15, quad = lane >> 4;

    const float* s0;
    if (SRCMODE == 0)      s0 = src + (size_t)jl * NC * HWP;
    else if (SRCMODE == 1) s0 = R + (size_t)b * NC * HWP;
    else                   s0 = S + (size_t)jl * NC * HWP;

    __shared__ _Float16 hh[8 * PL];
    __shared__ _Float16 ll[8 * PL];

    for (int t = tid; t < 360; t += 256) {
        int px = t >> 1, hf = t & 1;
        int hy = px / 18, hx = px - hy * 18;
        int gy = ty0 - 1 + hy, gx = tx0 - 1 + hx;
        bool ok = (gy >= 0 && gy < HH && gx >= 0 && gx < WW);
        const float* sp = s0 + (ok ? ((size_t)(gy * WW + gx) * 64) : 0) + hf * 32;
        int lb = px * 8;
#pragma unroll
        for (int c = 0; c < 4; ++c) {
            int cb = hf * 4 + c;
            floatx4 f0 = {0.f,0.f,0.f,0.f}, f1 = {0.f,0.f,0.f,0.f};
            if (ok) {
                f0 = *(const floatx4*)(sp + c * 8);
                f1 = *(const floatx4*)(sp + c * 8 + 4);
            }
            union { half8 v; _Float16 e[8]; } ph, pl;
#pragma unroll
            for (int j = 0; j < 4; ++j) {
                _Float16 h0 = (_Float16)f0[j], h1 = (_Float16)f1[j];
                ph.e[j] = h0;     ph.e[j+4] = h1;
                pl.e[j] = (_Float16)(f0[j] - (float)h0);
                pl.e[j+4] = (_Float16)(f1[j] - (float)h1);
            }
            *(half8*)&hh[cb * PL + lb] = ph.v;
            *(half8*)&ll[cb * PL + lb] = pl.v;
        }
    }
    __syncthreads();

    floatx4 acc0[NCT], acc1[NCT];
#pragma unroll
    for (int ct = 0; ct < NCT; ++ct) {
        acc0[ct] = floatx4{0.f, 0.f, 0.f, 0.f};
        acc1[ct] = floatx4{0.f, 0.f, 0.f, 0.f};
    }
    const int y0 = wq * 2, y1 = y0 + 1;

    half8 AhE[NCT], AlE[NCT], AhO[NCT], AlO[NCT];
    // prologue: A-batch for kc=0 into E
    {
        const _Float16* wk0 = wp + lane * 8;
#pragma unroll
        for (int ct = 0; ct < NCT; ++ct) {
            const _Float16* wc = wk0 + (size_t)ct * NKC * 1024;
            AhE[ct] = *(const half8*)wc;
            AlE[ct] = *(const half8*)(wc + 512);
        }
    }
#pragma unroll
    for (int kc2 = 0; kc2 < NKC; kc2 += 2) {
        // ---- even kc = kc2: prefetch O = A(kc2+1), MFMA from E ----
        {
            const int kc = kc2;
            const _Float16* wkn = wp + (size_t)(kc + 1) * 1024 + lane * 8;
#pragma unroll
            for (int ct = 0; ct < NCT; ++ct) {
                const _Float16* wc = wkn + (size_t)ct * NKC * 1024;
                AhO[ct] = *(const half8*)wc;
                AlO[ct] = *(const half8*)(wc + 512);
            }
            const int kk = kc >> 1;
            const int dy = kk / 3, dx = kk % 3;
            const int cb = ((kc & 1) << 2) + quad;
            const int ix0 = cb * PL + ((y0 + dy) * 18 + n + dx) * 8;
            const int ix1 = cb * PL + ((y1 + dy) * 18 + n + dx) * 8;
            half8 B0h = *(const half8*)&hh[ix0];
            half8 B0l = *(const half8*)&ll[ix0];
            half8 B1h = *(const half8*)&hh[ix1];
            half8 B1l = *(const half8*)&ll[ix1];
#pragma unroll
            for (int ct = 0; ct < NCT; ++ct) {
                acc0[ct] = __builtin_amdgcn_mfma_f32_16x16x32_f16(AhE[ct], B0h, acc0[ct], 0, 0, 0);
                acc0[ct] = __builtin_amdgcn_mfma_f32_16x16x32_f16(AhE[ct], B0l, acc0[ct], 0, 0, 0);
                acc0[ct] = __builtin_amdgcn_mfma_f32_16x16x32_f16(AlE[ct], B0h, acc0[ct], 0, 0, 0);
                acc1[ct] = __builtin_amdgcn_mfma_f32_16x16x32_f16(AhE[ct], B1h, acc1[ct], 0, 0, 0);
                acc1[ct] = __builtin_amdgcn_mfma_f32_16x16x32_f16(AhE[ct], B1l, acc1[ct], 0, 0, 0);
                acc1[ct] = __builtin_amdgcn_mfma_f32_16x16x32_f16(AlE[ct], B1h, acc1[ct], 0, 0, 0);
            }
        }
        // ---- odd kc = kc2+1: prefetch E = A(kc2+2) (if any), MFMA from O ----
        {
            const int kc = kc2 + 1;
            if (kc2 + 2 < NKC) {
                const _Float16* wkn = wp + (size_t)(kc2 + 2) * 1024 + lane * 8;
#pragma unroll
                for (int ct = 0; ct < NCT; ++ct) {
                    const _Float16* wc = wkn + (size_t)ct * NKC * 1024;
                    AhE[ct] = *(const half8*)wc;
                    AlE[ct] = *(const half8*)(wc + 512);
                }
            }
            const int kk = kc >> 1;
            const int dy = kk / 3, dx = kk % 3;
            const int cb = ((kc & 1) << 2) + quad;
            const int ix0 = cb * PL + ((y0 + dy) * 18 + n + dx) * 8;
            const int ix1 = cb * PL + ((y1 + dy) * 18 + n + dx) * 8;
            half8 B0h = *(const half8*)&hh[ix0];
            half8 B0l = *(const half8*)&ll[ix0];
            half8 B1h = *(const half8*)&hh[ix1];
            half8 B1l = *(const half8*)&ll[ix1];
#pragma unroll
            for (int ct = 0; ct < NCT; ++ct) {
                acc0[ct] = __builtin_amdgcn_mfma_f32_16x16x32_f16(AhO[ct], B0h, acc0[ct], 0, 0, 0);
                acc0[ct] = __builtin_amdgcn_mfma_f32_16x16x32_f16(AhO[ct], B0l, acc0[ct], 0, 0, 0);
                acc0[ct] = __builtin_amdgcn_mfma_f32_16x16x32_f16(AlO[ct], B0h, acc0[ct], 0, 0, 0);
                acc1[ct] = __builtin_amdgcn_mfma_f32_16x16x32_f16(AhO[ct], B1h, acc1[ct], 0, 0, 0);
                acc1[ct] = __builtin_amdgcn_mfma_f32_16x16x32_f16(AhO[ct], B1l, acc1[ct], 0, 0, 0);
                acc1[ct] = __builtin_amdgcn_mfma_f32_16x16x32_f16(AlO[ct], B1h, acc1[ct], 0, 0, 0);
            }
        }
    }

    const int oy0 = ty0 + y0, oy1 = ty0 + y1, ox = tx0 + n;
#pragma unroll
    for (int ct = 0; ct < NCT; ++ct) {
        const floatx4 b4 = *(const floatx4*)(bias + ct * 16 + quad * 4);
        float* op0 = out + ((size_t)jl * HWP + (size_t)oy0 * WW + ox) * Ct
                         + ct * 16 + quad * 4;
        float* op1 = out + ((size_t)jl * HWP + (size_t)oy1 * WW + ox) * Ct
                         + ct * 16 + quad * 4;
        floatx4 v0 = acc0[ct], v1 = acc1[ct];
        if (ADD) {
            v0 += *(const floatx4*)op0;
            v1 += *(const floatx4*)op1;
        } else {
            v0 += b4;
            v1 += b4;
        }
        *(floatx4*)op0 = v0;
        *(floatx4*)op1 = v1;
    }
}

// Deformable conv, MFMA phase B (split-fp16). CHANNEL-LAST.
// R16: LDS-STAGED GATHER (proven). R19: de-paired phase A (proven).
// R21: offset prefetch + unrolled phase A (proven). Final session state:
// structural floor for this decomposition — gather-transaction + LDS-
// conflict bound, all pipes <41%, four restructures (R14/R17/R20/R23)
// regressed against it.
__global__ __launch_bounds__(512, 4) void mdeform_k(
    const float* __restrict__ in, const float* __restrict__ off,
    const _Float16* __restrict__ wp, const float* __restrict__ bias,
    float* __restrict__ out, int supp_mode, const float* __restrict__ S)
{
    constexpr int SROW = 166;
    const int jl = blockIdx.y;
    const int tile = blockIdx.x;          // 16x16 tiles of 8x8
    const int ty0 = (tile >> 4) << 3, tx0 = (tile & 15) << 3;
    const int tid = threadIdx.x;
    const int lane = tid & 63;
    const int w8 = __builtin_amdgcn_readfirstlane(tid >> 6);  // wave 0..7
    const int q4 = w8 >> 1;               // co-tile 0..3
    const int sb2 = (w8 & 1) << 1;        // px-slot base: 0 or 2
    const int n = lane & 15, quad = lane >> 4;

    const float* ibase = supp_mode ? (S + (size_t)jl * NC * HWP)
                                   : (in + (size_t)jl * NC * HWP);
    const float* obase = off + (size_t)jl * OFFC * HWP;

    __shared__ _Float16 sh[64 * SROW];
    __shared__ _Float16 sl[64 * SROW];
    __shared__ float stg[256 * 16];       // 16x16 region x 16ch, quad-swizzled

    // zero pad K-slots [144,160)
    for (int e = tid; e < 64 * 16; e += 512) {
        int row = e >> 4, col = 144 + (e & 15);
        sh[row * SROW + col] = (_Float16)0.f;
        sl[row * SROW + col] = (_Float16)0.f;
    }

    floatx4 acc[2];
#pragma unroll
    for (int s = 0; s < 2; ++s) acc[s] = floatx4{0.f, 0.f, 0.f, 0.f};

    for (int r = 0; r < 4; ++r) {
        // ---- R21: prefetch this r's offsets (independent global loads; their
        // latency drains under the staging wait + barrier below)
        floatx2 o2v[3];
#pragma unroll
        for (int i = 0; i < 3; ++i) {
            int idx = tid + (i << 9);
            if (idx < 1152) {
                int gl = idx / 576;
                int rem = idx - gl * 576;
                int kk = rem >> 6;
                int px = rem & 63;
                int g = r * 2 + gl;
                int yy = ty0 + (px >> 3), xx = tx0 + (px & 7);
                o2v[i] = *(const floatx2*)(obase + (size_t)(yy * WW + xx) * OFFC
                                           + (g * 9 + kk) * 2);
            }
        }
        // ---- stage input region for this r's 16 channels (overlaps prev phase B)
#pragma unroll
        for (int j = 0; j < 2; ++j) {
            int t = tid + (j << 9);           // 0..1023
            int slot = t >> 2;                // 0..255 = ry*16+rx
            int qq = t & 3;
            int ry = slot >> 4, rx = slot & 15;
            int gy = ty0 - 4 + ry, gx = tx0 - 4 + rx;
            if ((unsigned)gy < (unsigned)HH && (unsigned)gx < (unsigned)WW) {
                floatx4 v = *(const floatx4*)(ibase + (size_t)(gy * WW + gx) * 64
                                              + r * 16 + qq * 4);
                *(floatx4*)&stg[(slot << 4) + ((qq ^ ((slot >> 1) & 3)) << 2)] = v;
            }
        }
        __syncthreads();   // staging visible; prev phase B done reading sh/sl
        // ---- phase A: de-paired tasks, UNROLLED. 1152 = 2(gl) x 9(kk) x 64(px)
#pragma unroll
        for (int i = 0; i < 3; ++i) {
            int idx = tid + (i << 9);         // 0..1535, active < 1152
            if (idx < 1152) {
                int gl = idx / 576;
                int rem = idx - gl * 576;
                int kk = rem >> 6;
                int px = rem & 63;
                int g = r * 2 + gl;
                int yy = ty0 + (px >> 3), xx = tx0 + (px & 7);
                floatx2 o2 = o2v[i];
                float pyf = (float)(yy + (kk / 3) - 1) + o2[0];
                float pxf = (float)(xx + (kk % 3) - 1) + o2[1];
                float fy = floorf(pyf), fx = floorf(pxf);
                float wy = pyf - fy, wx = pxf - fx;
                int y0 = (int)fy, x0 = (int)fx;
                int y1 = y0 + 1, x1 = x0 + 1;
                float m00 = (y0 >= 0 && y0 < HH && x0 >= 0 && x0 < WW) ? 1.f : 0.f;
                float m01 = (y0 >= 0 && y0 < HH && x1 >= 0 && x1 < WW) ? 1.f : 0.f;
                float m10 = (y1 >= 0 && y1 < HH && x0 >= 0 && x0 < WW) ? 1.f : 0.f;
                float m11 = (y1 >= 0 && y1 < HH && x1 >= 0 && x1 < WW) ? 1.f : 0.f;
                float w00 = (1.f - wy) * (1.f - wx) * m00;
                float w01 = (1.f - wy) * wx * m01;
                float w10 = wy * (1.f - wx) * m10;
                float w11 = wy * wx * m11;
                int cy0 = min(max(y0, 0), HH - 1), cy1 = min(max(y1, 0), HH - 1);
                int cx0 = min(max(x0, 0), WW - 1), cx1 = min(max(x1, 0), WW - 1);
                int ry0 = cy0 - ty0 + 4, ry1 = cy1 - ty0 + 4;
                int rx0 = cx0 - tx0 + 4, rx1 = cx1 - tx0 + 4;
                bool allin = ((unsigned)ry0 < 16u) & ((unsigned)ry1 < 16u) &
                             ((unsigned)rx0 < 16u) & ((unsigned)rx1 < 16u);
                const int qc = gl << 1;       // first channel-quad of this group
                floatx4 a0, b0, c0, d0, a1, b1, c1, d1;
                if (allin) {
                    int s00 = (ry0 << 4) + rx0, s01 = (ry0 << 4) + rx1;
                    int s10 = (ry1 << 4) + rx0, s11 = (ry1 << 4) + rx1;
                    int m0 = (s00 >> 1) & 3, m1 = (s01 >> 1) & 3;
                    int m2 = (s10 >> 1) & 3, m3 = (s11 >> 1) & 3;
                    a0 = *(const floatx4*)&stg[(s00 << 4) + ((qc ^ m0) << 2)];
                    a1 = *(const floatx4*)&stg[(s00 << 4) + (((qc + 1) ^ m0) << 2)];
                    b0 = *(const floatx4*)&stg[(s01 << 4) + ((qc ^ m1) << 2)];
                    b1 = *(const floatx4*)&stg[(s01 << 4) + (((qc + 1) ^ m1) << 2)];
                    c0 = *(const floatx4*)&stg[(s10 << 4) + ((qc ^ m2) << 2)];
                    c1 = *(const floatx4*)&stg[(s10 << 4) + (((qc + 1) ^ m2) << 2)];
                    d0 = *(const floatx4*)&stg[(s11 << 4) + ((qc ^ m3) << 2)];
                    d1 = *(const floatx4*)&stg[(s11 << 4) + (((qc + 1) ^ m3) << 2)];
                } else {
                    const int co = g * 8;
                    const float* p00 = ibase + (size_t)(cy0 * WW + cx0) * 64 + co;
                    const float* p01 = ibase + (size_t)(cy0 * WW + cx1) * 64 + co;
                    const float* p10 = ibase + (size_t)(cy1 * WW + cx0) * 64 + co;
                    const float* p11 = ibase + (size_t)(cy1 * WW + cx1) * 64 + co;
                    a0 = *(const floatx4*)p00;  a1 = *(const floatx4*)(p00 + 4);
                    b0 = *(const floatx4*)p01;  b1 = *(const floatx4*)(p01 + 4);
                    c0 = *(const floatx4*)p10;  c1 = *(const floatx4*)(p10 + 4);
                    d0 = *(const floatx4*)p11;  d1 = *(const floatx4*)(p11 + 4);
                }
                floatx4 sv0 = a0 * w00 + b0 * w01 + c0 * w10 + d0 * w11;
                floatx4 sv1 = a1 * w00 + b1 * w01 + c1 * w10 + d1 * w11;
                union { unsigned u[4]; _Float16 e[8]; } P, L;
#pragma unroll
                for (int j = 0; j < 4; ++j) {
                    _Float16 h0 = (_Float16)sv0[j];
                    _Float16 h1 = (_Float16)sv1[j];
                    P.e[j]     = h0;
                    P.e[j + 4] = h1;
                    L.e[j]     = (_Float16)(sv0[j] - (float)h0);
                    L.e[j + 4] = (_Float16)(sv1[j] - (float)h1);
                }
                int sb = px * SROW + gl * 72 + kk * 8;    // even -> 4-B aligned
                unsigned* shp = (unsigned*)&sh[sb];
                unsigned* slp = (unsigned*)&sl[sb];
                shp[0] = P.u[0]; shp[1] = P.u[1]; shp[2] = P.u[2]; shp[3] = P.u[3];
                slp[0] = L.u[0]; slp[1] = L.u[1]; slp[2] = L.u[2]; slp[3] = L.u[3];
            }
        }
        __syncthreads();
        // ---- phase B: MFMA contraction, wave w8 -> (co-tile q4, px-slots sb2..sb2+1)
#pragma unroll
        for (int kc5 = 0; kc5 < 5; ++kc5) {
            int kcg = r * 5 + kc5;
            size_t base = (size_t)((q4 * 20 + kcg) * 2) * 512;
            half8 Ah = *(const half8*)(wp + base + lane * 8);
            half8 Al = *(const half8*)(wp + base + 512 + lane * 8);
#pragma unroll
            for (int s = 0; s < 2; ++s) {
                int px = (sb2 + s) * 16 + n;
                const int ix = px * SROW + kc5 * 32 + quad * 8;
                half8 Bh = *(const half8*)&sh[ix];
                half8 Bl = *(const half8*)&sl[ix];
                acc[s] = __builtin_amdgcn_mfma_f32_16x16x32_f16(Ah, Bh, acc[s], 0, 0, 0);
                acc[s] = __builtin_amdgcn_mfma_f32_16x16x32_f16(Ah, Bl, acc[s], 0, 0, 0);
                acc[s] = __builtin_amdgcn_mfma_f32_16x16x32_f16(Al, Bh, acc[s], 0, 0, 0);
            }
        }
    }
    const floatx4 b4 = *(const floatx4*)(bias + q4 * 16 + quad * 4);
#pragma unroll
    for (int s = 0; s < 2; ++s) {
        int px = (sb2 + s) * 16 + n;
        int oy = ty0 + (px >> 3), ox = tx0 + (px & 7);
        float* op = out + ((size_t)jl * HWP + (size_t)oy * WW + ox) * 64
                        + q4 * 16 + quad * 4;
        *(floatx4*)op = acc[s] + b4;
    }
}

// rec conv (64 -> 3): fp32, channel-last input. Writes d_out (planar).
__global__ __launch_bounds__(256) void conv3x3_rec_k(
    const float* __restrict__ in, const float* __restrict__ w,
    const float* __restrict__ bias, float* __restrict__ out, int job0)
{
    constexpr int CB = 8;
    constexpr int PITCH = 48;
    constexpr int CH = 18 * PITCH;
    const int jl = blockIdx.y, jg = job0 + jl;
    const int b = jg & 1, fi = jg >> 1;
    const int frame = fi + (fi >= 2 ? 1 : 0);
    const int tile = blockIdx.x;
    const int ty0 = (tile >> 3) << 4, tx0 = (tile & 7) << 4;
    const int tid = threadIdx.x;
    const int tx = tid & 15, ty = tid >> 4;
    const float* srcA = in + (size_t)jl * NC * HWP;

    __shared__ float lds[CB * CH];
    float acc[3] = {bias[0], bias[1], bias[2]};

    for (int cb = 0; cb < NC; cb += CB) {
        __syncthreads();
        for (int e = tid; e < CB * 324; e += 256) {
            int c = e & 7;
            int r = e >> 3;
            int iy = r / 18, ix = r - iy * 18;
            int gy = ty0 - 1 + iy, gx = tx0 - 1 + ix;
            float v = 0.f;
            if (gy >= 0 && gy < HH && gx >= 0 && gx < WW)
                v = srcA[(size_t)(gy * WW + gx) * 64 + cb + c];
            lds[c * CH + iy * PITCH + ix] = v;
        }
        __syncthreads();
#pragma unroll
        for (int c = 0; c < CB; ++c) {
            float t[9];
#pragma unroll
            for (int dy = 0; dy < 3; ++dy)
#pragma unroll
                for (int dx = 0; dx < 3; ++dx)
                    t[dy * 3 + dx] = lds[c * CH + (ty + dy) * PITCH + (tx + dx)];
            int ci = cb + c;
#pragma unroll
            for (int o = 0; o < 3; ++o) {
                const float* wo = w + ((size_t)o * NC + ci) * 9;
#pragma unroll
                for (int kk = 0; kk < 9; ++kk)
                    acc[o] = fmaf(wo[kk], t[kk], acc[o]);
            }
        }
    }
    const int oy = ty0 + ty, ox = tx0 + tx;
#pragma unroll
    for (int o = 0; o < 3; ++o)
        out[((size_t)(b * NN + frame) * 3 + o) * HWP + oy * WW + ox] = acc[o];
}

extern "C" void kernel_launch(void* const* d_in, const int* in_sizes, int n_in,
                              void* d_out, int out_size, void* d_ws, size_t ws_size,
                              hipStream_t stream)
{
    const float* pf    = (const float*)d_in[0];
    const float* xc    = (const float*)d_in[1];
    const float* cr_w  = (const float*)d_in[2];
    const float* cr_b  = (const float*)d_in[3];
    const float* ow[4] = {(const float*)d_in[4],  (const float*)d_in[8],
                          (const float*)d_in[12], (const float*)d_in[16]};
    const float* ob[4] = {(const float*)d_in[5],  (const float*)d_in[9],
                          (const float*)d_in[13], (const float*)d_in[17]};
    const float* dw[4] = {(const float*)d_in[6],  (const float*)d_in[10],
                          (const float*)d_in[14], (const float*)d_in[18]};
    const float* db[4] = {(const float*)d_in[7],  (const float*)d_in[11],
                          (const float*)d_in[15], (const float*)d_in[19]};
    const float* rec_w = (const float*)d_in[20];
    const float* rec_b = (const float*)d_in[21];
    float* out = (float*)d_out;

    // ws layout: [wp cr x2][wp of x4][wp dc x4][R 2][S JC][A JC][Bb JC][O JC]
    const size_t WPC = (size_t)4 * NKC * 1024;
    const size_t WPO = (size_t)9 * NKC * 1024;
    const size_t WPD = (size_t)4 * 20 * 1024;
    _Float16* wp_cr0 = (_Float16*)d_ws;
    _Float16* wp_cr1 = wp_cr0 + WPC;
    _Float16* wp_of[4];
    _Float16* wp_dc[4];
    _Float16* curh = wp_cr1 + WPC;
    for (int i = 0; i < 4; ++i) { wp_of[i] = curh; curh += WPO; }
    for (int i = 0; i < 4; ++i) { wp_dc[i] = curh; curh += WPD; }
    size_t wp_bytes = (size_t)((char*)curh - (char*)d_ws);

    const size_t fplane = (size_t)NC * HWP;
    const size_t oplane = (size_t)OFFC * HWP;
    int JC = 8;
    while (JC > 1 &&
           wp_bytes + (2 + 3 * (size_t)JC) * fplane * 4 + (size_t)JC * oplane * 4 > ws_size)
        JC >>= 1;
    float* R  = (float*)curh;
    float* S  = R  + 2 * fplane;
    float* A  = S  + (size_t)JC * fplane;
    float* Bb = A  + (size_t)JC * fplane;
    float* O  = Bb + (size_t)JC * fplane;

    // ---- weight preprocessing + ref repack (every call; ws re-poisoned) ----
    {
        int nc4 = 4 * NKC * 64, nc9 = 9 * NKC * 64, ncd = 4 * 20 * 64;
        dim3 b4((nc4 + 255) / 256), b9((nc9 + 255) / 256), bd((ncd + 255) / 256);
        prew_k<<<b4, 256, 0, stream>>>(cr_w, wp_cr0, 4, NKC, 0, 0, 128);
        prew_k<<<b4, 256, 0, stream>>>(cr_w, wp_cr1, 4, NKC, 0, 64, 128);
        for (int i = 0; i < 4; ++i) {
            prew_k<<<b9, 256, 0, stream>>>(ow[i], wp_of[i], 9, NKC, 0, 0, 64);
            prew_k<<<bd, 256, 0, stream>>>(dw[i], wp_dc[i], 4, 20, 1, 0, 64);
        }
        repack_k<<<dim3(256, 2), 256, 0, stream>>>(pf, R, 0, 1);
    }

    copy_center_k<<<dim3((NB * 3 * HWP + 255) / 256), 256, 0, stream>>>(xc, out);

    for (int job0 = 0; job0 < 8; job0 += JC) {
        dim3 blk(256);
        dim3 blk512(512);
        dim3 gconv(128, JC), gdef(256, JC), grec(64, JC);
        repack_k<<<dim3(256, JC), blk, 0, stream>>>(pf, S, job0, 0);
        // fea1 = cr_conv(concat(ref, supp)) : two K=576 passes (ref, then supp ADD)
        mconv_k<4, 1, 0><<<gconv, blk, 0, stream>>>(nullptr, R, S, wp_cr0, cr_b, A, job0);
        mconv_k<4, 2, 1><<<gconv, blk, 0, stream>>>(nullptr, R, S, wp_cr1, cr_b, A, job0);
        // off1(fea1); fea2 = deform(fea1)
        mconv_k<9, 0, 0><<<gconv, blk, 0, stream>>>(A, R, S, wp_of[0], ob[0], O, job0);
        mdeform_k<<<gdef, blk512, 0, stream>>>(A, O, wp_dc[0], db[0], Bb, 0, S);
        // off2(fea2); fea3 = deform(fea2)
        mconv_k<9, 0, 0><<<gconv, blk, 0, stream>>>(Bb, R, S, wp_of[1], ob[1], O, job0);
        mdeform_k<<<gdef, blk512, 0, stream>>>(Bb, O, wp_dc[1], db[1], A, 0, S);
        // off3(fea3); fea4 = deform(supp)
        mconv_k<9, 0, 0><<<gconv, blk, 0, stream>>>(A, R, S, wp_of[2], ob[2], O, job0);
        mdeform_k<<<gdef, blk512, 0, stream>>>(nullptr, O, wp_dc[2], db[2], Bb, 1, S);
        // off4(fea4); aligned = deform(fea4)
        mconv_k<9, 0, 0><<<gconv, blk, 0, stream>>>(Bb, R, S, wp_of[3], ob[3], O, job0);
        mdeform_k<<<gdef, blk512, 0, stream>>>(Bb, O, wp_dc[3], db[3], A, 0, S);
        // out[b, frame] = rec_conv(aligned)
        conv3x3_rec_k<<<grec, blk, 0, stream>>>(A, rec_w, rec_b, out, job0);
    }
}